// Round 10
// baseline (387.804 us; speedup 1.0000x reference)
//
#include <hip/hip_runtime.h>
#include <math.h>

#define L_SEQ 1600
#define CDIM 256
#define NH 8
#define HD 32
#define GRID_H 40
#define GRID_W 40
#define DFF_ 1024
#define SCALE_QK 0.17677669529663687f

typedef __attribute__((ext_vector_type(8))) short short8;
typedef __attribute__((ext_vector_type(4))) float f32x4;

__device__ __forceinline__ float waveReduceSum(float v) {
#pragma unroll
    for (int off = 32; off > 0; off >>= 1) v += __shfl_down(v, off, 64);
    return v;
}
__device__ __forceinline__ float blockReduceSum(float v, float* sh4) {
    v = waveReduceSum(v);
    int lane = threadIdx.x & 63, wid = threadIdx.x >> 6;
    __syncthreads();
    if (lane == 0) sh4[wid] = v;
    __syncthreads();
    return sh4[0] + sh4[1] + sh4[2] + sh4[3];
}

__device__ __forceinline__ unsigned short f2bf(float x) {
    union { float f; unsigned u; } v; v.f = x;
    unsigned r = (v.u + 0x7FFFu + ((v.u >> 16) & 1u)) >> 16;
    return (unsigned short)r;
}
__device__ __forceinline__ unsigned pkbf(float lo, float hi) {
    return (unsigned)f2bf(lo) | ((unsigned)f2bf(hi) << 16);
}

// LayerNorm over C=256; one block per row. out2 = out + addin (optional)
__global__ __launch_bounds__(256) void ln_kernel(const float* __restrict__ x,
                                                 const float* __restrict__ g,
                                                 const float* __restrict__ b,
                                                 const float* __restrict__ addin,
                                                 float* __restrict__ out,
                                                 float* __restrict__ out2) {
    __shared__ float sh4[4];
    int row = blockIdx.x;
    int c = threadIdx.x;
    float v = x[row * CDIM + c];
    float mean = blockReduceSum(v, sh4) * (1.0f / CDIM);
    float d = v - mean;
    float var = blockReduceSum(d * d, sh4) * (1.0f / CDIM);
    float y = d * rsqrtf(var + 1e-5f) * g[c] + b[c];
    out[row * CDIM + c] = y;
    if (out2) out2[row * CDIM + c] = y + addin[row * CDIM + c];
}

// ---------------------------------------------------------------------------
// bf16 MFMA GEMM, batched up to 3 jobs via blockIdx.z (verified body).
// ---------------------------------------------------------------------------
struct GJob {
    const float* A; const float* W; const float* bias; const float* res;
    float* C; int N; int K;
};

__global__ __launch_bounds__(256) void gemm_mfma(GJob j0, GJob j1, GJob j2) {
    GJob j = j0;
    if (blockIdx.z == 1) j = j1;
    else if (blockIdx.z == 2) j = j2;
    const float* __restrict__ A = j.A;
    const float* __restrict__ W = j.W;
    const float* bias = j.bias;
    const float* res = j.res;
    float* __restrict__ C = j.C;
    int N = j.N, K = j.K;

    __shared__ unsigned short Al[2][4][64][8];
    __shared__ unsigned short Bl[2][4][64][8];
    int tid = threadIdx.x;
    int bm = blockIdx.y * 64, bn = blockIdx.x * 64;
    if (bn >= N) return;
    int lane = tid & 63, wave = tid >> 6;
    int wr = wave >> 1, wc = wave & 1;

    int srow = tid >> 3;
    int q = tid & 7;
    int e0 = (q & 1) * 4;

    f32x4 acc[2][2] = {};
    int nsteps = K >> 5;

    float4 ra[2], rb[2];
    {
#pragma unroll
        for (int r = 0; r < 2; ++r) {
            int row = srow + 32 * r;
            ra[r] = *(const float4*)(A + (bm + row) * K + 4 * q);
            int n = bn + row;
            rb[r] = (n < N) ? *(const float4*)(W + n * K + 4 * q)
                            : make_float4(0.f, 0.f, 0.f, 0.f);
        }
#pragma unroll
        for (int r = 0; r < 2; ++r) {
            int row = srow + 32 * r;
            int frag = (row >> 4), l = (row & 15) + 16 * (q >> 1);
            *(uint2*)&Al[0][frag][l][e0] = make_uint2(pkbf(ra[r].x, ra[r].y), pkbf(ra[r].z, ra[r].w));
            *(uint2*)&Bl[0][frag][l][e0] = make_uint2(pkbf(rb[r].x, rb[r].y), pkbf(rb[r].z, rb[r].w));
        }
    }
    __syncthreads();

    for (int s = 0; s < nsteps; ++s) {
        bool more = (s + 1) < nsteps;
        if (more) {
            int k0 = (s + 1) << 5;
#pragma unroll
            for (int r = 0; r < 2; ++r) {
                int row = srow + 32 * r;
                ra[r] = *(const float4*)(A + (bm + row) * K + k0 + 4 * q);
                int n = bn + row;
                rb[r] = (n < N) ? *(const float4*)(W + n * K + k0 + 4 * q)
                                : make_float4(0.f, 0.f, 0.f, 0.f);
            }
        }
        {
            int buf = s & 1;
            short8 af[2], bfr[2];
#pragma unroll
            for (int i = 0; i < 2; ++i) {
                af[i] = *(const short8*)&Al[buf][2 * wr + i][lane][0];
                bfr[i] = *(const short8*)&Bl[buf][2 * wc + i][lane][0];
            }
#pragma unroll
            for (int i = 0; i < 2; ++i)
#pragma unroll
                for (int jj = 0; jj < 2; ++jj)
                    acc[i][jj] = __builtin_amdgcn_mfma_f32_16x16x32_bf16(af[i], bfr[jj], acc[i][jj], 0, 0, 0);
        }
        if (more) {
            int buf = (s + 1) & 1;
#pragma unroll
            for (int r = 0; r < 2; ++r) {
                int row = srow + 32 * r;
                int frag = (row >> 4), l = (row & 15) + 16 * (q >> 1);
                *(uint2*)&Al[buf][frag][l][e0] = make_uint2(pkbf(ra[r].x, ra[r].y), pkbf(ra[r].z, ra[r].w));
                *(uint2*)&Bl[buf][frag][l][e0] = make_uint2(pkbf(rb[r].x, rb[r].y), pkbf(rb[r].z, rb[r].w));
            }
        }
        __syncthreads();
    }

#pragma unroll
    for (int jj = 0; jj < 2; ++jj) {
        int col = bn + wc * 32 + jj * 16 + (lane & 15);
        if (col >= N) continue;
        float bv = bias ? bias[col] : 0.f;
#pragma unroll
        for (int i = 0; i < 2; ++i) {
            int rbase = bm + wr * 32 + i * 16 + ((lane >> 4) << 2);
#pragma unroll
            for (int r = 0; r < 4; ++r) {
                int row = rbase + r;
                float v = acc[i][jj][r] + bv;
                if (res) v += res[row * N + col];
                C[row * N + col] = v;
            }
        }
    }
}

// ---------------------------------------------------------------------------
// MFMA flash attention, QBLK=64 (4 q-frags/wave), optional id-gating fused
// into K/V staging (idkv != null: K *= 1+tanh(id_k[h]); V += id_v).
// Per-operand strides so Q/K/V can read straight from the qv buffer.
// ---------------------------------------------------------------------------
#define QBLK 64
#define KTJ 128
__global__ __launch_bounds__(256) void mha_mfma(const float* __restrict__ Q, int ldq,
                                                const float* __restrict__ K, int ldk,
                                                const float* __restrict__ V, int ldv,
                                                const float* __restrict__ idkv,
                                                float* __restrict__ O, int ldo) {
    __shared__ unsigned short Kl[8][64][8];       // 8 KB
    __shared__ unsigned short Vl[4][2][64][12];   // 12 KB
    __shared__ float mred[4][4][16];              // 1 KB
    __shared__ float lred[4][4][16];              // 1 KB
    __shared__ float Osh[3][2][4][64][4];         // 24 KB
    int h = blockIdx.y;
    int qbase = blockIdx.x * QBLK;
    int tid = threadIdx.x;
    int w = tid >> 6, lane = tid & 63;
    int g = lane >> 4, c = lane & 15;

    short8 qfrag[4];
#pragma unroll
    for (int qt = 0; qt < 4; ++qt) {
        const float* qp = Q + (qbase + qt * 16 + c) * ldq + h * HD + g * 8;
        float4 f0 = *(const float4*)qp;
        float4 f1 = *(const float4*)(qp + 4);
        short8 s;
        s[0] = (short)f2bf(f0.x * SCALE_QK); s[1] = (short)f2bf(f0.y * SCALE_QK);
        s[2] = (short)f2bf(f0.z * SCALE_QK); s[3] = (short)f2bf(f0.w * SCALE_QK);
        s[4] = (short)f2bf(f1.x * SCALE_QK); s[5] = (short)f2bf(f1.y * SCALE_QK);
        s[6] = (short)f2bf(f1.z * SCALE_QK); s[7] = (short)f2bf(f1.w * SCALE_QK);
        qfrag[qt] = s;
    }

    float m[4] = { -INFINITY, -INFINITY, -INFINITY, -INFINITY };
    float l[4] = { 0.f, 0.f, 0.f, 0.f };
    f32x4 acc_o[2][4] = {};

    int jrow = tid >> 1;
    int dhalf = (tid & 1) * 16;
    int vjq = tid >> 3;
    int vdq = tid & 7;
    int vjr = 4 * vjq;
    int vd0 = 4 * vdq;
    int vjc = vjr >> 5, vdt = vd0 >> 4, vjg = (vjr & 31) >> 3, ve0 = vjr & 7;

    int src_lo = 16 * ((2 * g) & 3) + c;
    int src_hi = 16 * ((2 * g + 1) & 3) + c;
    bool hisel = (g >= 2);

    for (int t = 0; t < L_SEQ; t += KTJ) {
        // ---- stage K (gated if idkv) ----
        {
            int jj = t + jrow;
            float4 f0, f1, f2, f3;
            if (jj < L_SEQ) {
                const float4* kp = (const float4*)(K + jj * ldk + h * HD + dhalf);
                f0 = kp[0]; f1 = kp[1]; f2 = kp[2]; f3 = kp[3];
                if (idkv) {
                    float gt = 1.f + tanhf(idkv[jj * 264 + h]);
                    f0.x *= gt; f0.y *= gt; f0.z *= gt; f0.w *= gt;
                    f1.x *= gt; f1.y *= gt; f1.z *= gt; f1.w *= gt;
                    f2.x *= gt; f2.y *= gt; f2.z *= gt; f2.w *= gt;
                    f3.x *= gt; f3.y *= gt; f3.z *= gt; f3.w *= gt;
                }
            } else {
                f0 = f1 = f2 = f3 = make_float4(0.f, 0.f, 0.f, 0.f);
            }
            int jt = jrow >> 4;
            int laneA = (jrow & 15) + dhalf * 2;
            short8 s0, s1;
            s0[0]=f2bf(f0.x); s0[1]=f2bf(f0.y); s0[2]=f2bf(f0.z); s0[3]=f2bf(f0.w);
            s0[4]=f2bf(f1.x); s0[5]=f2bf(f1.y); s0[6]=f2bf(f1.z); s0[7]=f2bf(f1.w);
            s1[0]=f2bf(f2.x); s1[1]=f2bf(f2.y); s1[2]=f2bf(f2.z); s1[3]=f2bf(f2.w);
            s1[4]=f2bf(f3.x); s1[5]=f2bf(f3.y); s1[6]=f2bf(f3.z); s1[7]=f2bf(f3.w);
            *(short8*)&Kl[jt][laneA][0] = s0;
            *(short8*)&Kl[jt][laneA + 16][0] = s1;
        }
        // ---- stage V (transposed; +id_v if idkv) ----
        {
            float4 rr[4];
            int j0 = t + vjr;
#pragma unroll
            for (int r = 0; r < 4; ++r) {
                int jj = j0 + r;
                if (jj < L_SEQ) {
                    float4 fv = *(const float4*)(V + jj * ldv + h * HD + vd0);
                    if (idkv) {
                        float4 av = *(const float4*)(idkv + jj * 264 + 8 + h * HD + vd0);
                        fv.x += av.x; fv.y += av.y; fv.z += av.z; fv.w += av.w;
                    }
                    rr[r] = fv;
                } else {
                    rr[r] = make_float4(0.f, 0.f, 0.f, 0.f);
                }
            }
            float col[4][4] = {
                { rr[0].x, rr[1].x, rr[2].x, rr[3].x },
                { rr[0].y, rr[1].y, rr[2].y, rr[3].y },
                { rr[0].z, rr[1].z, rr[2].z, rr[3].z },
                { rr[0].w, rr[1].w, rr[2].w, rr[3].w } };
#pragma unroll
            for (int dd = 0; dd < 4; ++dd) {
                int laneV = ((vd0 + dd) & 15) + 16 * vjg;
                uint2 pk;
                pk.x = pkbf(col[dd][0], col[dd][1]);
                pk.y = pkbf(col[dd][2], col[dd][3]);
                *(uint2*)&Vl[vjc][vdt][laneV][ve0] = pk;
            }
        }
        __syncthreads();

        bool alive = (t + 32 * w) < L_SEQ;
        if (alive) {
            short8 kf0 = *(const short8*)&Kl[2 * w][lane][0];
            short8 kf1 = *(const short8*)&Kl[2 * w + 1][lane][0];
            f32x4 zero = { 0.f, 0.f, 0.f, 0.f };
            f32x4 s[2][4];
#pragma unroll
            for (int qt = 0; qt < 4; ++qt) {
                s[0][qt] = __builtin_amdgcn_mfma_f32_16x16x32_bf16(kf0, qfrag[qt], zero, 0, 0, 0);
                s[1][qt] = __builtin_amdgcn_mfma_f32_16x16x32_bf16(kf1, qfrag[qt], zero, 0, 0, 0);
            }

            short8 pfrag[4];
#pragma unroll
            for (int qt = 0; qt < 4; ++qt) {
                float mx = s[0][qt][0];
                mx = fmaxf(mx, s[0][qt][1]); mx = fmaxf(mx, s[0][qt][2]); mx = fmaxf(mx, s[0][qt][3]);
                mx = fmaxf(mx, s[1][qt][0]); mx = fmaxf(mx, s[1][qt][1]);
                mx = fmaxf(mx, s[1][qt][2]); mx = fmaxf(mx, s[1][qt][3]);
                mx = fmaxf(mx, __shfl_xor(mx, 16, 64));
                mx = fmaxf(mx, __shfl_xor(mx, 32, 64));
                float nm = fmaxf(m[qt], mx);
                float alpha = __expf(m[qt] - nm);
                m[qt] = nm;
                float p00 = __expf(s[0][qt][0] - nm), p01 = __expf(s[0][qt][1] - nm);
                float p02 = __expf(s[0][qt][2] - nm), p03 = __expf(s[0][qt][3] - nm);
                float p10 = __expf(s[1][qt][0] - nm), p11 = __expf(s[1][qt][1] - nm);
                float p12 = __expf(s[1][qt][2] - nm), p13 = __expf(s[1][qt][3] - nm);
                float ts = ((p00 + p01) + (p02 + p03)) + ((p10 + p11) + (p12 + p13));
                ts += __shfl_xor(ts, 16, 64);
                ts += __shfl_xor(ts, 32, 64);
                l[qt] = l[qt] * alpha + ts;
#pragma unroll
                for (int dt = 0; dt < 2; ++dt) {
                    acc_o[dt][qt][0] *= alpha; acc_o[dt][qt][1] *= alpha;
                    acc_o[dt][qt][2] *= alpha; acc_o[dt][qt][3] *= alpha;
                }
                unsigned w00 = pkbf(p00, p01), w01 = pkbf(p02, p03);
                unsigned w10 = pkbf(p10, p11), w11 = pkbf(p12, p13);
                unsigned a0 = __shfl(w00, src_lo, 64);
                unsigned a1 = __shfl(w10, src_lo, 64);
                unsigned b0 = __shfl(w01, src_lo, 64);
                unsigned b1 = __shfl(w11, src_lo, 64);
                unsigned c0 = __shfl(w00, src_hi, 64);
                unsigned c1 = __shfl(w10, src_hi, 64);
                unsigned d0 = __shfl(w01, src_hi, 64);
                unsigned d1 = __shfl(w11, src_hi, 64);
                union { short8 s8; unsigned u[4]; } P;
                P.u[0] = hisel ? a1 : a0;
                P.u[1] = hisel ? b1 : b0;
                P.u[2] = hisel ? c1 : c0;
                P.u[3] = hisel ? d1 : d0;
                pfrag[qt] = P.s8;
            }

            union { short8 s8; uint2 v[2]; } vf0u, vf1u;
            vf0u.v[0] = *(const uint2*)&Vl[w][0][lane][0];
            vf0u.v[1] = *(const uint2*)&Vl[w][0][lane][4];
            vf1u.v[0] = *(const uint2*)&Vl[w][1][lane][0];
            vf1u.v[1] = *(const uint2*)&Vl[w][1][lane][4];
#pragma unroll
            for (int qt = 0; qt < 4; ++qt) {
                acc_o[0][qt] = __builtin_amdgcn_mfma_f32_16x16x32_bf16(vf0u.s8, pfrag[qt], acc_o[0][qt], 0, 0, 0);
                acc_o[1][qt] = __builtin_amdgcn_mfma_f32_16x16x32_bf16(vf1u.s8, pfrag[qt], acc_o[1][qt], 0, 0, 0);
            }
        }
        __syncthreads();
    }

    if (g == 0) {
#pragma unroll
        for (int qt = 0; qt < 4; ++qt) { mred[w][qt][c] = m[qt]; lred[w][qt][c] = l[qt]; }
    }
    if (w > 0) {
#pragma unroll
        for (int dt = 0; dt < 2; ++dt)
#pragma unroll
            for (int qt = 0; qt < 4; ++qt)
                *(f32x4*)&Osh[w - 1][dt][qt][lane][0] = acc_o[dt][qt];
    }
    __syncthreads();
    if (w == 0) {
#pragma unroll
        for (int qt = 0; qt < 4; ++qt) {
            float m0_ = mred[0][qt][c], m1_ = mred[1][qt][c];
            float m2_ = mred[2][qt][c], m3_ = mred[3][qt][c];
            float M = fmaxf(fmaxf(m0_, m1_), fmaxf(m2_, m3_));
            float a0 = __expf(m0_ - M), a1 = __expf(m1_ - M);
            float a2 = __expf(m2_ - M), a3 = __expf(m3_ - M);
            float L = a0 * lred[0][qt][c] + a1 * lred[1][qt][c]
                    + a2 * lred[2][qt][c] + a3 * lred[3][qt][c];
            float inv = 1.f / L;
#pragma unroll
            for (int dt = 0; dt < 2; ++dt) {
                f32x4 o1 = *(const f32x4*)&Osh[0][dt][qt][lane][0];
                f32x4 o2 = *(const f32x4*)&Osh[1][dt][qt][lane][0];
                f32x4 o3 = *(const f32x4*)&Osh[2][dt][qt][lane][0];
                float4 r;
                r.x = (acc_o[dt][qt][0] * a0 + o1[0] * a1 + o2[0] * a2 + o3[0] * a3) * inv;
                r.y = (acc_o[dt][qt][1] * a0 + o1[1] * a1 + o2[1] * a2 + o3[1] * a3) * inv;
                r.z = (acc_o[dt][qt][2] * a0 + o1[2] * a1 + o2[2] * a2 + o3[2] * a3) * inv;
                r.w = (acc_o[dt][qt][3] * a0 + o1[3] * a1 + o2[3] * a2 + o3[3] * a3) * inv;
                *(float4*)(O + (qbase + qt * 16 + c) * ldo + h * HD + dt * 16 + 4 * g) = r;
            }
        }
    }
}

// ---------------------------------------------------------------------------
// MFMA local windowed attention (verified; + strides and fused id-gating)
// ---------------------------------------------------------------------------
__global__ __launch_bounds__(256, 1) void local_mfma(const float* __restrict__ Q, int ldq,
                                                     const float* __restrict__ K, int ldk,
                                                     const float* __restrict__ V, int ldv,
                                                     const float* __restrict__ idkv,
                                                     float* __restrict__ O, int ldo) {
    __shared__ unsigned short Kp[768 * 40];
    __shared__ unsigned short Vt[32 * 776];
    __shared__ float mred[4][3][16];
    __shared__ float lred[4][3][16];
    __shared__ float Osh[3][2][3][64][4];
    int y = blockIdx.x, h = blockIdx.y;
    int tid = threadIdx.x;
    int w = tid >> 6, lane = tid & 63;
    int g = lane >> 4, c = lane & 15;

#pragma unroll 4
    for (int rep = 0; rep < 24; ++rep) {
        int idx = rep * 256 + tid;
        int key = idx >> 3, dq = idx & 7;
        int ky = key / 48;
        int xx = key - 48 * ky;
        int yy = y + ky - 7;
        bool ok = (xx < 40) && (yy >= 0) && (yy < 40);
        float4 fk = make_float4(0.f, 0.f, 0.f, 0.f);
        float4 fv = make_float4(0.f, 0.f, 0.f, 0.f);
        if (ok) {
            int row = yy * 40 + xx;
            fk = *(const float4*)(K + row * ldk + h * HD + 4 * dq);
            fv = *(const float4*)(V + row * ldv + h * HD + 4 * dq);
            if (idkv) {
                float gt = 1.f + tanhf(idkv[row * 264 + h]);
                fk.x *= gt; fk.y *= gt; fk.z *= gt; fk.w *= gt;
                float4 av = *(const float4*)(idkv + row * 264 + 8 + h * HD + 4 * dq);
                fv.x += av.x; fv.y += av.y; fv.z += av.z; fv.w += av.w;
            }
        }
        *(uint2*)&Kp[key * 40 + 4 * dq] = make_uint2(pkbf(fk.x, fk.y), pkbf(fk.z, fk.w));
        int vb = (4 * dq) * 776 + key;
        Vt[vb] = f2bf(fv.x);
        Vt[vb + 776] = f2bf(fv.y);
        Vt[vb + 1552] = f2bf(fv.z);
        Vt[vb + 2328] = f2bf(fv.w);
    }

    short8 qfrag[3];
#pragma unroll
    for (int qt = 0; qt < 3; ++qt) {
        short8 s = { 0, 0, 0, 0, 0, 0, 0, 0 };
        int qx = qt * 16 + c;
        if (qx < 40) {
            const float* qp = Q + (y * 40 + qx) * ldq + h * HD + g * 8;
            float4 f0 = *(const float4*)qp;
            float4 f1 = *(const float4*)(qp + 4);
            s[0] = (short)f2bf(f0.x * SCALE_QK); s[1] = (short)f2bf(f0.y * SCALE_QK);
            s[2] = (short)f2bf(f0.z * SCALE_QK); s[3] = (short)f2bf(f0.w * SCALE_QK);
            s[4] = (short)f2bf(f1.x * SCALE_QK); s[5] = (short)f2bf(f1.y * SCALE_QK);
            s[6] = (short)f2bf(f1.z * SCALE_QK); s[7] = (short)f2bf(f1.w * SCALE_QK);
        }
        qfrag[qt] = s;
    }
    __syncthreads();

    f32x4 sfr[12][3];
    const f32x4 zf = { 0.f, 0.f, 0.f, 0.f };
#pragma unroll
    for (int i = 0; i < 12; ++i) {
        int ky = 4 * w + i / 3;
        int fx = i % 3;
        short8 kf = *(const short8*)&Kp[(ky * 48 + fx * 16 + c) * 40 + 8 * g];
#pragma unroll
        for (int qt = 0; qt < 3; ++qt)
            sfr[i][qt] = __builtin_amdgcn_mfma_f32_16x16x32_bf16(kf, qfrag[qt], zf, 0, 0, 0);
    }

    float mw[3] = { -1e30f, -1e30f, -1e30f };
#pragma unroll
    for (int i = 0; i < 12; ++i) {
        int ky = 4 * w + i / 3, fx = i % 3;
        int yy = y + ky - 7;
        bool rowok = (yy >= 0) && (yy < 40);
        int xxb = fx * 16 + 4 * g;
#pragma unroll
        for (int qt = 0; qt < 3; ++qt) {
            int qx = qt * 16 + c;
#pragma unroll
            for (int r = 0; r < 4; ++r) {
                int xx = xxb + r;
                int dd = xx - qx;
                bool ok = rowok && (xx < 40) && (dd <= 7) && (dd >= -7);
                float v = ok ? sfr[i][qt][r] : -1e9f;
                sfr[i][qt][r] = v;
                mw[qt] = fmaxf(mw[qt], v);
            }
        }
    }
#pragma unroll
    for (int qt = 0; qt < 3; ++qt) {
        mw[qt] = fmaxf(mw[qt], __shfl_xor(mw[qt], 16, 64));
        mw[qt] = fmaxf(mw[qt], __shfl_xor(mw[qt], 32, 64));
    }
    if (lane < 16) {
#pragma unroll
        for (int qt = 0; qt < 3; ++qt) mred[w][qt][lane] = mw[qt];
    }
    __syncthreads();
    float M[3];
#pragma unroll
    for (int qt = 0; qt < 3; ++qt)
        M[qt] = fmaxf(fmaxf(mred[0][qt][c], mred[1][qt][c]),
                      fmaxf(mred[2][qt][c], mred[3][qt][c]));

    float lsum[3] = { 0.f, 0.f, 0.f };
    f32x4 acc_o[2][3] = {};
    int src_lo = 16 * ((2 * g) & 3) + c;
    int src_hi = 16 * ((2 * g + 1) & 3) + c;
    bool hisel = (g >= 2);
#pragma unroll
    for (int chk = 0; chk < 6; ++chk) {
        short8 pfrag[3];
#pragma unroll
        for (int qt = 0; qt < 3; ++qt) {
            float p00 = __expf(sfr[2 * chk][qt][0] - M[qt]);
            float p01 = __expf(sfr[2 * chk][qt][1] - M[qt]);
            float p02 = __expf(sfr[2 * chk][qt][2] - M[qt]);
            float p03 = __expf(sfr[2 * chk][qt][3] - M[qt]);
            float p10 = __expf(sfr[2 * chk + 1][qt][0] - M[qt]);
            float p11 = __expf(sfr[2 * chk + 1][qt][1] - M[qt]);
            float p12 = __expf(sfr[2 * chk + 1][qt][2] - M[qt]);
            float p13 = __expf(sfr[2 * chk + 1][qt][3] - M[qt]);
            lsum[qt] += ((p00 + p01) + (p02 + p03)) + ((p10 + p11) + (p12 + p13));
            unsigned w00 = pkbf(p00, p01), w01 = pkbf(p02, p03);
            unsigned w10 = pkbf(p10, p11), w11 = pkbf(p12, p13);
            unsigned a0 = __shfl(w00, src_lo, 64);
            unsigned a1 = __shfl(w10, src_lo, 64);
            unsigned b0 = __shfl(w01, src_lo, 64);
            unsigned b1 = __shfl(w11, src_lo, 64);
            unsigned c0 = __shfl(w00, src_hi, 64);
            unsigned c1 = __shfl(w10, src_hi, 64);
            unsigned d0 = __shfl(w01, src_hi, 64);
            unsigned d1 = __shfl(w11, src_hi, 64);
            union { short8 s8; unsigned u[4]; } P;
            P.u[0] = hisel ? a1 : a0;
            P.u[1] = hisel ? b1 : b0;
            P.u[2] = hisel ? c1 : c0;
            P.u[3] = hisel ? d1 : d0;
            pfrag[qt] = P.s8;
        }
        int jb = 32 * (6 * w + chk);
        short8 vf0 = *(const short8*)&Vt[c * 776 + jb + 8 * g];
        short8 vf1 = *(const short8*)&Vt[(16 + c) * 776 + jb + 8 * g];
#pragma unroll
        for (int qt = 0; qt < 3; ++qt) {
            acc_o[0][qt] = __builtin_amdgcn_mfma_f32_16x16x32_bf16(vf0, pfrag[qt], acc_o[0][qt], 0, 0, 0);
            acc_o[1][qt] = __builtin_amdgcn_mfma_f32_16x16x32_bf16(vf1, pfrag[qt], acc_o[1][qt], 0, 0, 0);
        }
    }

#pragma unroll
    for (int qt = 0; qt < 3; ++qt) {
        lsum[qt] += __shfl_xor(lsum[qt], 16, 64);
        lsum[qt] += __shfl_xor(lsum[qt], 32, 64);
    }
    if (lane < 16) {
#pragma unroll
        for (int qt = 0; qt < 3; ++qt) lred[w][qt][lane] = lsum[qt];
    }
    if (w > 0) {
#pragma unroll
        for (int dt = 0; dt < 2; ++dt)
#pragma unroll
            for (int qt = 0; qt < 3; ++qt)
                *(f32x4*)&Osh[w - 1][dt][qt][lane][0] = acc_o[dt][qt];
    }
    __syncthreads();
    if (w == 0) {
#pragma unroll
        for (int qt = 0; qt < 3; ++qt) {
            int qx = qt * 16 + c;
            if (qx >= 40) continue;
            float L = (lred[0][qt][c] + lred[1][qt][c]) + (lred[2][qt][c] + lred[3][qt][c]);
            float inv = 1.f / L;
#pragma unroll
            for (int dt = 0; dt < 2; ++dt) {
                f32x4 o1 = *(const f32x4*)&Osh[0][dt][qt][lane][0];
                f32x4 o2 = *(const f32x4*)&Osh[1][dt][qt][lane][0];
                f32x4 o3 = *(const f32x4*)&Osh[2][dt][qt][lane][0];
                float4 r;
                r.x = (acc_o[dt][qt][0] + o1[0] + o2[0] + o3[0]) * inv;
                r.y = (acc_o[dt][qt][1] + o1[1] + o2[1] + o3[1]) * inv;
                r.z = (acc_o[dt][qt][2] + o1[2] + o2[2] + o3[2]) * inv;
                r.w = (acc_o[dt][qt][3] + o1[3] + o2[3] + o3[3]) * inv;
                *(float4*)(O + (y * 40 + qx) * ldo + h * HD + dt * 16 + 4 * g) = r;
            }
        }
    }
}

// merged prep: dw_k transpose + [lt|st] weight concat + bias sum
__global__ __launch_bounds__(256) void prep_misc(const float* __restrict__ Kw,
                                                 const float* __restrict__ lt_wo,
                                                 const float* __restrict__ lt_bo,
                                                 const float* __restrict__ st_wo,
                                                 const float* __restrict__ st_bo,
                                                 float* __restrict__ Kt,
                                                 float* __restrict__ wcat,
                                                 float* __restrict__ bsum) {
    int idx = blockIdx.x * 256 + threadIdx.x;   // 0..65535
    int n = idx >> 8, k = idx & 255;
    wcat[n * 512 + k] = lt_wo[idx];
    wcat[n * 512 + 256 + k] = st_wo[idx];
    if (idx < 256) bsum[idx] = lt_bo[idx] + st_bo[idx];
    if (idx < 25 * DFF_) {
        int kk = idx >> 10, c = idx & 1023;
        Kt[idx] = Kw[c * 25 + kk];
    }
}

// GroupNorm partials: grid (32 groups, 8 chunks); deterministic partial sums.
__global__ __launch_bounds__(256) void gn_partial(const float* __restrict__ X,
                                                  float* __restrict__ gstat) {
    __shared__ float sh4[4];
    int g = blockIdx.x, chunk = blockIdx.y;
    int base = g * 32;
    float s = 0.f, s2 = 0.f;
    for (int i = threadIdx.x; i < 200 * 32; i += 256) {
        int l = chunk * 200 + (i >> 5), c = i & 31;
        float v = X[l * DFF_ + base + c];
        s += v;
        s2 += v * v;
    }
    s = blockReduceSum(s, sh4);
    s2 = blockReduceSum(s2, sh4);
    if (threadIdx.x == 0) {
        gstat[g * 8 + chunk] = s;
        gstat[256 + g * 8 + chunk] = s2;
    }
}

// GroupNorm apply + exact GELU, float4-vectorized.
__global__ __launch_bounds__(256) void gn_apply(const float* __restrict__ X,
                                                const float* __restrict__ gstat,
                                                const float* __restrict__ g,
                                                const float* __restrict__ b,
                                                float* __restrict__ Y) {
    int idx = blockIdx.x * 256 + threadIdx.x;
    int e4 = idx * 4;
    int c = e4 & 1023;
    int grp = c >> 5;
    float s = 0.f, s2 = 0.f;
#pragma unroll
    for (int i = 0; i < 8; ++i) {
        s += gstat[grp * 8 + i];
        s2 += gstat[256 + grp * 8 + i];
    }
    const float invn = 1.0f / 51200.f;
    float mean = s * invn;
    float rs = rsqrtf(s2 * invn - mean * mean + 1e-5f);
    float4 v = *(const float4*)(X + e4);
    float4 gg = *(const float4*)(g + c);
    float4 bb = *(const float4*)(b + c);
    float4 r;
    float y0 = (v.x - mean) * rs * gg.x + bb.x;
    float y1 = (v.y - mean) * rs * gg.y + bb.y;
    float y2 = (v.z - mean) * rs * gg.z + bb.z;
    float y3 = (v.w - mean) * rs * gg.w + bb.w;
    r.x = 0.5f * y0 * (1.0f + erff(y0 * 0.70710678118654752f));
    r.y = 0.5f * y1 * (1.0f + erff(y1 * 0.70710678118654752f));
    r.z = 0.5f * y2 * (1.0f + erff(y2 * 0.70710678118654752f));
    r.w = 0.5f * y3 * (1.0f + erff(y3 * 0.70710678118654752f));
    *(float4*)(Y + e4) = r;
}

// depthwise 5x5 conv v2 (verified)
__global__ __launch_bounds__(256) void dwconv_v2(const float* __restrict__ X,
                                                 const float* __restrict__ Kt,
                                                 float* __restrict__ Y) {
    int l = blockIdx.x;
    int c4 = threadIdx.x * 4;
    int y = l / GRID_W, x = l - y * GRID_W;
    float4 acc = make_float4(0.f, 0.f, 0.f, 0.f);
    if (y >= 2 && y < GRID_H - 2 && x >= 2 && x < GRID_W - 2) {
#pragma unroll
        for (int ky = 0; ky < 5; ++ky) {
#pragma unroll
            for (int kx = 0; kx < 5; ++kx) {
                float4 xv = *(const float4*)(X + ((y + ky - 2) * GRID_W + x + kx - 2) * DFF_ + c4);
                float4 wv = *(const float4*)(Kt + (ky * 5 + kx) * DFF_ + c4);
                acc.x += xv.x * wv.x; acc.y += xv.y * wv.y;
                acc.z += xv.z * wv.z; acc.w += xv.w * wv.w;
            }
        }
    } else {
#pragma unroll
        for (int ky = 0; ky < 5; ++ky) {
            int yy = y + ky - 2;
            if (yy < 0 || yy >= GRID_H) continue;
#pragma unroll
            for (int kx = 0; kx < 5; ++kx) {
                int xx = x + kx - 2;
                if (xx < 0 || xx >= GRID_W) continue;
                float4 xv = *(const float4*)(X + (yy * GRID_W + xx) * DFF_ + c4);
                float4 wv = *(const float4*)(Kt + (ky * 5 + kx) * DFF_ + c4);
                acc.x += xv.x * wv.x; acc.y += xv.y * wv.y;
                acc.z += xv.z * wv.z; acc.w += xv.w * wv.w;
            }
        }
    }
    *(float4*)(Y + l * DFF_ + c4) = acc;
}

extern "C" void kernel_launch(void* const* d_in, const int* in_sizes, int n_in,
                              void* d_out, int out_size, void* d_ws, size_t ws_size,
                              hipStream_t stream) {
    (void)in_sizes; (void)n_in; (void)out_size; (void)ws_size;
    const float* tgt = (const float*)d_in[0];
    const float* curr_id_emb = (const float*)d_in[1];
    const float* self_pos = (const float*)d_in[2];
    const float* ln1_g = (const float*)d_in[3];
    const float* ln1_b = (const float*)d_in[4];
    const float* sa_wq = (const float*)d_in[5];
    const float* sa_bq = (const float*)d_in[6];
    const float* sa_wk = (const float*)d_in[7];
    const float* sa_bk = (const float*)d_in[8];
    const float* sa_wv = (const float*)d_in[9];
    const float* sa_bv = (const float*)d_in[10];
    const float* sa_wo = (const float*)d_in[11];
    const float* sa_bo = (const float*)d_in[12];
    const float* ln2_g = (const float*)d_in[13];
    const float* ln2_b = (const float*)d_in[14];
    const float* w_qv = (const float*)d_in[15];
    const float* b_qv = (const float*)d_in[16];
    const float* w_id = (const float*)d_in[17];
    const float* b_id = (const float*)d_in[18];
    const float* lt_wo = (const float*)d_in[19];
    const float* lt_bo = (const float*)d_in[20];
    const float* st_wo = (const float*)d_in[21];
    const float* st_bo = (const float*)d_in[22];
    const float* ln3_g = (const float*)d_in[23];
    const float* ln3_b = (const float*)d_in[24];
    const float* w1 = (const float*)d_in[25];
    const float* b1 = (const float*)d_in[26];
    const float* gn_g = (const float*)d_in[27];
    const float* gn_b = (const float*)d_in[28];
    const float* dw_k = (const float*)d_in[29];
    const float* w2 = (const float*)d_in[30];
    const float* b2 = (const float*)d_in[31];
    float* out = (float*)d_out;

    float* ws = (float*)d_ws;
    const int LC = L_SEQ * CDIM;           // 409600
    float* bufA = ws;                      // ln outputs
    float* bufB = bufA + LC;               // qk_in / tgt_b
    float* bufC = bufB + LC;               // q_
    float* bufD = bufC + LC;               // k_
    float* bufE = bufD + LC;               // v_
    float* bufG = bufE + LC;               // tgt1
    float* bufFW = bufG + LC;              // attn outs (1600x512)
    float* bufH = bufFW + L_SEQ * 512;     // qv (1600x512); later gstat
    float* bufI = bufH + L_SEQ * 512;      // idkv (1600x264)
    float* bufX = bufI + L_SEQ * 264;      // w1 out (1600x1024)
    float* bufY = bufX + L_SEQ * DFF_;     // gn+gelu out
    float* bufZ = bufY + L_SEQ * DFF_;     // conv out
    float* bufW = bufZ + L_SEQ * DFF_;     // transposed dw_k (25x1024)
    float* wcat = bufW + 25 * DFF_;        // concat lt/st weights (256x512)
    float* bsum = wcat + 256 * 512;        // summed biases (256)

    dim3 blk(256);
    dim3 mhaGrid(L_SEQ / QBLK, NH);        // (25, 8)
    auto J = [](const float* A, const float* W, const float* bias, const float* res,
                float* C, int N, int K) {
        GJob j; j.A = A; j.W = W; j.bias = bias; j.res = res; j.C = C; j.N = N; j.K = K;
        return j;
    };

    // 0. merged prep (independent)
    prep_misc<<<256, blk, 0, stream>>>(dw_k, lt_wo, lt_bo, st_wo, st_bo, bufW, wcat, bsum);
    // 1. LN1: bufA = ln(tgt), bufB = bufA + self_pos
    ln_kernel<<<L_SEQ, blk, 0, stream>>>(tgt, ln1_g, ln1_b, self_pos, bufA, bufB);
    // 2. q,k,v projections (one batched dispatch, 300 blocks)
    {
        GJob jq = J(bufB, sa_wq, sa_bq, nullptr, bufC, CDIM, CDIM);
        GJob jk = J(bufB, sa_wk, sa_bk, nullptr, bufD, CDIM, CDIM);
        GJob jv = J(bufA, sa_wv, sa_bv, nullptr, bufE, CDIM, CDIM);
        gemm_mfma<<<dim3(4, 25, 3), blk, 0, stream>>>(jq, jk, jv);
    }
    // 3. self attention -> bufFW (ldo=256)
    mha_mfma<<<mhaGrid, blk, 0, stream>>>(bufC, CDIM, bufD, CDIM, bufE, CDIM, nullptr, bufFW, CDIM);
    // 4. out proj + residual -> tgt1 (bufG)
    {
        GJob jo = J(bufFW, sa_wo, sa_bo, tgt, bufG, CDIM, CDIM);
        gemm_mfma<<<dim3(4, 25, 1), blk, 0, stream>>>(jo, jo, jo);
    }
    // 5. LN2 -> bufA
    ln_kernel<<<L_SEQ, blk, 0, stream>>>(bufG, ln2_g, ln2_b, nullptr, bufA, nullptr);
    // 6. qv + idkv (one batched dispatch)
    {
        GJob jqv = J(bufA, w_qv, b_qv, nullptr, bufH, 512, CDIM);
        GJob jid = J(curr_id_emb, w_id, b_id, nullptr, bufI, 264, CDIM);
        gemm_mfma<<<dim3(8, 25, 2), blk, 0, stream>>>(jqv, jid, jid);
    }
    // 7. long-term attention (gating fused) -> bufFW cols 0..255
    mha_mfma<<<mhaGrid, blk, 0, stream>>>(bufH, 512, bufH, 512, bufH + 256, 512, bufI, bufFW, 512);
    // 8. local attention (gating fused) -> bufFW cols 256..511
    local_mfma<<<dim3(GRID_H, NH), blk, 0, stream>>>(bufH, 512, bufH, 512, bufH + 256, 512, bufI, bufFW + 256, 512);
    // 9. merged lt/st projection: tgt_b = tgt1 + [mha2|local] @ wcat^T + bsum -> bufB
    {
        GJob jm = J(bufFW, wcat, bsum, bufG, bufB, CDIM, 512);
        gemm_mfma<<<dim3(4, 25, 1), blk, 0, stream>>>(jm, jm, jm);
    }
    // 10. LN3 -> bufA
    ln_kernel<<<L_SEQ, blk, 0, stream>>>(bufB, ln3_g, ln3_b, nullptr, bufA, nullptr);
    // 11. x = bufA @ w1^T -> bufX
    {
        GJob jw1 = J(bufA, w1, b1, nullptr, bufX, DFF_, CDIM);
        gemm_mfma<<<dim3(16, 25, 1), blk, 0, stream>>>(jw1, jw1, jw1);
    }
    // 12. GroupNorm + GELU -> bufY (bufH dead; reuse as gstat)
    gn_partial<<<dim3(32, 8), blk, 0, stream>>>(bufX, bufH);
    gn_apply<<<L_SEQ, blk, 0, stream>>>(bufX, bufH, gn_g, gn_b, bufY);
    // 13. depthwise conv -> bufZ
    dwconv_v2<<<L_SEQ, blk, 0, stream>>>(bufY, bufW, bufZ);
    // 14. final proj + residual(tgt_b) -> out
    {
        GJob jw2 = J(bufZ, w2, b2, bufB, out, CDIM, DFF_);
        gemm_mfma<<<dim3(4, 25, 1), blk, 0, stream>>>(jw2, jw2, jw2);
    }
}

// Round 11
// 377.491 us; speedup vs baseline: 1.0273x; 1.0273x over previous
//
#include <hip/hip_runtime.h>
#include <math.h>

#define L_SEQ 1600
#define CDIM 256
#define NH 8
#define HD 32
#define GRID_H 40
#define GRID_W 40
#define DFF_ 1024
#define SCALE_QK 0.17677669529663687f

typedef __attribute__((ext_vector_type(8))) short short8;
typedef __attribute__((ext_vector_type(4))) float f32x4;

__device__ __forceinline__ float waveReduceSum(float v) {
#pragma unroll
    for (int off = 32; off > 0; off >>= 1) v += __shfl_down(v, off, 64);
    return v;
}
__device__ __forceinline__ float blockReduceSum(float v, float* sh4) {
    v = waveReduceSum(v);
    int lane = threadIdx.x & 63, wid = threadIdx.x >> 6;
    __syncthreads();
    if (lane == 0) sh4[wid] = v;
    __syncthreads();
    return sh4[0] + sh4[1] + sh4[2] + sh4[3];
}

__device__ __forceinline__ unsigned short f2bf(float x) {
    union { float f; unsigned u; } v; v.f = x;
    unsigned r = (v.u + 0x7FFFu + ((v.u >> 16) & 1u)) >> 16;
    return (unsigned short)r;
}
__device__ __forceinline__ unsigned pkbf(float lo, float hi) {
    return (unsigned)f2bf(lo) | ((unsigned)f2bf(hi) << 16);
}

// LayerNorm over C=256; one block per row. out2 = out + addin (optional)
__global__ __launch_bounds__(256) void ln_kernel(const float* __restrict__ x,
                                                 const float* __restrict__ g,
                                                 const float* __restrict__ b,
                                                 const float* __restrict__ addin,
                                                 float* __restrict__ out,
                                                 float* __restrict__ out2) {
    __shared__ float sh4[4];
    int row = blockIdx.x;
    int c = threadIdx.x;
    float v = x[row * CDIM + c];
    float mean = blockReduceSum(v, sh4) * (1.0f / CDIM);
    float d = v - mean;
    float var = blockReduceSum(d * d, sh4) * (1.0f / CDIM);
    float y = d * rsqrtf(var + 1e-5f) * g[c] + b[c];
    out[row * CDIM + c] = y;
    if (out2) out2[row * CDIM + c] = y + addin[row * CDIM + c];
}

// ---------------------------------------------------------------------------
// bf16 MFMA GEMM, batched up to 3 jobs via blockIdx.z (verified body).
// ---------------------------------------------------------------------------
struct GJob {
    const float* A; const float* W; const float* bias; const float* res;
    float* C; int N; int K;
};

__global__ __launch_bounds__(256) void gemm_mfma(GJob j0, GJob j1, GJob j2) {
    GJob j = j0;
    if (blockIdx.z == 1) j = j1;
    else if (blockIdx.z == 2) j = j2;
    const float* __restrict__ A = j.A;
    const float* __restrict__ W = j.W;
    const float* bias = j.bias;
    const float* res = j.res;
    float* __restrict__ C = j.C;
    int N = j.N, K = j.K;

    __shared__ unsigned short Al[2][4][64][8];
    __shared__ unsigned short Bl[2][4][64][8];
    int tid = threadIdx.x;
    int bm = blockIdx.y * 64, bn = blockIdx.x * 64;
    if (bn >= N) return;
    int lane = tid & 63, wave = tid >> 6;
    int wr = wave >> 1, wc = wave & 1;

    int srow = tid >> 3;
    int q = tid & 7;
    int e0 = (q & 1) * 4;

    f32x4 acc[2][2] = {};
    int nsteps = K >> 5;

    float4 ra[2], rb[2];
    {
#pragma unroll
        for (int r = 0; r < 2; ++r) {
            int row = srow + 32 * r;
            ra[r] = *(const float4*)(A + (bm + row) * K + 4 * q);
            int n = bn + row;
            rb[r] = (n < N) ? *(const float4*)(W + n * K + 4 * q)
                            : make_float4(0.f, 0.f, 0.f, 0.f);
        }
#pragma unroll
        for (int r = 0; r < 2; ++r) {
            int row = srow + 32 * r;
            int frag = (row >> 4), l = (row & 15) + 16 * (q >> 1);
            *(uint2*)&Al[0][frag][l][e0] = make_uint2(pkbf(ra[r].x, ra[r].y), pkbf(ra[r].z, ra[r].w));
            *(uint2*)&Bl[0][frag][l][e0] = make_uint2(pkbf(rb[r].x, rb[r].y), pkbf(rb[r].z, rb[r].w));
        }
    }
    __syncthreads();

    for (int s = 0; s < nsteps; ++s) {
        bool more = (s + 1) < nsteps;
        if (more) {
            int k0 = (s + 1) << 5;
#pragma unroll
            for (int r = 0; r < 2; ++r) {
                int row = srow + 32 * r;
                ra[r] = *(const float4*)(A + (bm + row) * K + k0 + 4 * q);
                int n = bn + row;
                rb[r] = (n < N) ? *(const float4*)(W + n * K + k0 + 4 * q)
                                : make_float4(0.f, 0.f, 0.f, 0.f);
            }
        }
        {
            int buf = s & 1;
            short8 af[2], bfr[2];
#pragma unroll
            for (int i = 0; i < 2; ++i) {
                af[i] = *(const short8*)&Al[buf][2 * wr + i][lane][0];
                bfr[i] = *(const short8*)&Bl[buf][2 * wc + i][lane][0];
            }
#pragma unroll
            for (int i = 0; i < 2; ++i)
#pragma unroll
                for (int jj = 0; jj < 2; ++jj)
                    acc[i][jj] = __builtin_amdgcn_mfma_f32_16x16x32_bf16(af[i], bfr[jj], acc[i][jj], 0, 0, 0);
        }
        if (more) {
            int buf = (s + 1) & 1;
#pragma unroll
            for (int r = 0; r < 2; ++r) {
                int row = srow + 32 * r;
                int frag = (row >> 4), l = (row & 15) + 16 * (q >> 1);
                *(uint2*)&Al[buf][frag][l][e0] = make_uint2(pkbf(ra[r].x, ra[r].y), pkbf(ra[r].z, ra[r].w));
                *(uint2*)&Bl[buf][frag][l][e0] = make_uint2(pkbf(rb[r].x, rb[r].y), pkbf(rb[r].z, rb[r].w));
            }
        }
        __syncthreads();
    }

#pragma unroll
    for (int jj = 0; jj < 2; ++jj) {
        int col = bn + wc * 32 + jj * 16 + (lane & 15);
        if (col >= N) continue;
        float bv = bias ? bias[col] : 0.f;
#pragma unroll
        for (int i = 0; i < 2; ++i) {
            int rbase = bm + wr * 32 + i * 16 + ((lane >> 4) << 2);
#pragma unroll
            for (int r = 0; r < 4; ++r) {
                int row = rbase + r;
                float v = acc[i][jj][r] + bv;
                if (res) v += res[row * N + col];
                C[row * N + col] = v;
            }
        }
    }
}

// ---------------------------------------------------------------------------
// MFMA flash attention, QBLK=32 (measured-good), strides + fused id-gating.
// ---------------------------------------------------------------------------
#define QBLK 32
#define KTJ 128
__global__ __launch_bounds__(256) void mha_mfma(const float* __restrict__ Q, int ldq,
                                                const float* __restrict__ K, int ldk,
                                                const float* __restrict__ V, int ldv,
                                                const float* __restrict__ idkv,
                                                float* __restrict__ O, int ldo) {
    __shared__ unsigned short Kl[8][64][8];
    __shared__ unsigned short Vl[4][2][64][12];
    __shared__ float mred[4][2][16];
    __shared__ float lred[4][2][16];
    __shared__ float Osh[3][2][2][64][4];
    int h = blockIdx.y;
    int qbase = blockIdx.x * QBLK;
    int tid = threadIdx.x;
    int w = tid >> 6, lane = tid & 63;
    int g = lane >> 4, c = lane & 15;

    short8 qfrag[2];
#pragma unroll
    for (int qt = 0; qt < 2; ++qt) {
        const float* qp = Q + (qbase + qt * 16 + c) * ldq + h * HD + g * 8;
        float4 f0 = *(const float4*)qp;
        float4 f1 = *(const float4*)(qp + 4);
        short8 s;
        s[0] = (short)f2bf(f0.x * SCALE_QK); s[1] = (short)f2bf(f0.y * SCALE_QK);
        s[2] = (short)f2bf(f0.z * SCALE_QK); s[3] = (short)f2bf(f0.w * SCALE_QK);
        s[4] = (short)f2bf(f1.x * SCALE_QK); s[5] = (short)f2bf(f1.y * SCALE_QK);
        s[6] = (short)f2bf(f1.z * SCALE_QK); s[7] = (short)f2bf(f1.w * SCALE_QK);
        qfrag[qt] = s;
    }

    float m[2] = { -INFINITY, -INFINITY };
    float l[2] = { 0.f, 0.f };
    f32x4 acc_o[2][2] = {};

    int jrow = tid >> 1;
    int dhalf = (tid & 1) * 16;
    int vjq = tid >> 3;
    int vdq = tid & 7;
    int vjr = 4 * vjq;
    int vd0 = 4 * vdq;
    int vjc = vjr >> 5, vdt = vd0 >> 4, vjg = (vjr & 31) >> 3, ve0 = vjr & 7;

    int src_lo = 16 * ((2 * g) & 3) + c;
    int src_hi = 16 * ((2 * g + 1) & 3) + c;
    bool hisel = (g >= 2);

    for (int t = 0; t < L_SEQ; t += KTJ) {
        // ---- stage K (gated if idkv) ----
        {
            int jj = t + jrow;
            float4 f0, f1, f2, f3;
            if (jj < L_SEQ) {
                const float4* kp = (const float4*)(K + jj * ldk + h * HD + dhalf);
                f0 = kp[0]; f1 = kp[1]; f2 = kp[2]; f3 = kp[3];
                if (idkv) {
                    float gt = 1.f + tanhf(idkv[jj * 264 + h]);
                    f0.x *= gt; f0.y *= gt; f0.z *= gt; f0.w *= gt;
                    f1.x *= gt; f1.y *= gt; f1.z *= gt; f1.w *= gt;
                    f2.x *= gt; f2.y *= gt; f2.z *= gt; f2.w *= gt;
                    f3.x *= gt; f3.y *= gt; f3.z *= gt; f3.w *= gt;
                }
            } else {
                f0 = f1 = f2 = f3 = make_float4(0.f, 0.f, 0.f, 0.f);
            }
            int jt = jrow >> 4;
            int laneA = (jrow & 15) + dhalf * 2;
            short8 s0, s1;
            s0[0]=f2bf(f0.x); s0[1]=f2bf(f0.y); s0[2]=f2bf(f0.z); s0[3]=f2bf(f0.w);
            s0[4]=f2bf(f1.x); s0[5]=f2bf(f1.y); s0[6]=f2bf(f1.z); s0[7]=f2bf(f1.w);
            s1[0]=f2bf(f2.x); s1[1]=f2bf(f2.y); s1[2]=f2bf(f2.z); s1[3]=f2bf(f2.w);
            s1[4]=f2bf(f3.x); s1[5]=f2bf(f3.y); s1[6]=f2bf(f3.z); s1[7]=f2bf(f3.w);
            *(short8*)&Kl[jt][laneA][0] = s0;
            *(short8*)&Kl[jt][laneA + 16][0] = s1;
        }
        // ---- stage V (transposed; +id_v if idkv) ----
        {
            float4 rr[4];
            int j0 = t + vjr;
#pragma unroll
            for (int r = 0; r < 4; ++r) {
                int jj = j0 + r;
                if (jj < L_SEQ) {
                    float4 fv = *(const float4*)(V + jj * ldv + h * HD + vd0);
                    if (idkv) {
                        float4 av = *(const float4*)(idkv + jj * 264 + 8 + h * HD + vd0);
                        fv.x += av.x; fv.y += av.y; fv.z += av.z; fv.w += av.w;
                    }
                    rr[r] = fv;
                } else {
                    rr[r] = make_float4(0.f, 0.f, 0.f, 0.f);
                }
            }
            float col[4][4] = {
                { rr[0].x, rr[1].x, rr[2].x, rr[3].x },
                { rr[0].y, rr[1].y, rr[2].y, rr[3].y },
                { rr[0].z, rr[1].z, rr[2].z, rr[3].z },
                { rr[0].w, rr[1].w, rr[2].w, rr[3].w } };
#pragma unroll
            for (int dd = 0; dd < 4; ++dd) {
                int laneV = ((vd0 + dd) & 15) + 16 * vjg;
                uint2 pk;
                pk.x = pkbf(col[dd][0], col[dd][1]);
                pk.y = pkbf(col[dd][2], col[dd][3]);
                *(uint2*)&Vl[vjc][vdt][laneV][ve0] = pk;
            }
        }
        __syncthreads();

        bool alive = (t + 32 * w) < L_SEQ;
        if (alive) {
            short8 kf0 = *(const short8*)&Kl[2 * w][lane][0];
            short8 kf1 = *(const short8*)&Kl[2 * w + 1][lane][0];
            f32x4 zero = { 0.f, 0.f, 0.f, 0.f };
            f32x4 s[2][2];
            s[0][0] = __builtin_amdgcn_mfma_f32_16x16x32_bf16(kf0, qfrag[0], zero, 0, 0, 0);
            s[0][1] = __builtin_amdgcn_mfma_f32_16x16x32_bf16(kf0, qfrag[1], zero, 0, 0, 0);
            s[1][0] = __builtin_amdgcn_mfma_f32_16x16x32_bf16(kf1, qfrag[0], zero, 0, 0, 0);
            s[1][1] = __builtin_amdgcn_mfma_f32_16x16x32_bf16(kf1, qfrag[1], zero, 0, 0, 0);

            short8 pfrag[2];
#pragma unroll
            for (int qt = 0; qt < 2; ++qt) {
                float mx = s[0][qt][0];
                mx = fmaxf(mx, s[0][qt][1]); mx = fmaxf(mx, s[0][qt][2]); mx = fmaxf(mx, s[0][qt][3]);
                mx = fmaxf(mx, s[1][qt][0]); mx = fmaxf(mx, s[1][qt][1]);
                mx = fmaxf(mx, s[1][qt][2]); mx = fmaxf(mx, s[1][qt][3]);
                mx = fmaxf(mx, __shfl_xor(mx, 16, 64));
                mx = fmaxf(mx, __shfl_xor(mx, 32, 64));
                float nm = fmaxf(m[qt], mx);
                float alpha = __expf(m[qt] - nm);
                m[qt] = nm;
                float p00 = __expf(s[0][qt][0] - nm), p01 = __expf(s[0][qt][1] - nm);
                float p02 = __expf(s[0][qt][2] - nm), p03 = __expf(s[0][qt][3] - nm);
                float p10 = __expf(s[1][qt][0] - nm), p11 = __expf(s[1][qt][1] - nm);
                float p12 = __expf(s[1][qt][2] - nm), p13 = __expf(s[1][qt][3] - nm);
                float ts = ((p00 + p01) + (p02 + p03)) + ((p10 + p11) + (p12 + p13));
                ts += __shfl_xor(ts, 16, 64);
                ts += __shfl_xor(ts, 32, 64);
                l[qt] = l[qt] * alpha + ts;
#pragma unroll
                for (int dt = 0; dt < 2; ++dt) {
                    acc_o[dt][qt][0] *= alpha; acc_o[dt][qt][1] *= alpha;
                    acc_o[dt][qt][2] *= alpha; acc_o[dt][qt][3] *= alpha;
                }
                unsigned w00 = pkbf(p00, p01), w01 = pkbf(p02, p03);
                unsigned w10 = pkbf(p10, p11), w11 = pkbf(p12, p13);
                unsigned a0 = __shfl(w00, src_lo, 64);
                unsigned a1 = __shfl(w10, src_lo, 64);
                unsigned b0 = __shfl(w01, src_lo, 64);
                unsigned b1 = __shfl(w11, src_lo, 64);
                unsigned c0 = __shfl(w00, src_hi, 64);
                unsigned c1 = __shfl(w10, src_hi, 64);
                unsigned d0 = __shfl(w01, src_hi, 64);
                unsigned d1 = __shfl(w11, src_hi, 64);
                union { short8 s8; unsigned u[4]; } P;
                P.u[0] = hisel ? a1 : a0;
                P.u[1] = hisel ? b1 : b0;
                P.u[2] = hisel ? c1 : c0;
                P.u[3] = hisel ? d1 : d0;
                pfrag[qt] = P.s8;
            }

            union { short8 s8; uint2 v[2]; } vf0u, vf1u;
            vf0u.v[0] = *(const uint2*)&Vl[w][0][lane][0];
            vf0u.v[1] = *(const uint2*)&Vl[w][0][lane][4];
            vf1u.v[0] = *(const uint2*)&Vl[w][1][lane][0];
            vf1u.v[1] = *(const uint2*)&Vl[w][1][lane][4];
            acc_o[0][0] = __builtin_amdgcn_mfma_f32_16x16x32_bf16(vf0u.s8, pfrag[0], acc_o[0][0], 0, 0, 0);
            acc_o[0][1] = __builtin_amdgcn_mfma_f32_16x16x32_bf16(vf0u.s8, pfrag[1], acc_o[0][1], 0, 0, 0);
            acc_o[1][0] = __builtin_amdgcn_mfma_f32_16x16x32_bf16(vf1u.s8, pfrag[0], acc_o[1][0], 0, 0, 0);
            acc_o[1][1] = __builtin_amdgcn_mfma_f32_16x16x32_bf16(vf1u.s8, pfrag[1], acc_o[1][1], 0, 0, 0);
        }
        __syncthreads();
    }

    if (g == 0) {
#pragma unroll
        for (int qt = 0; qt < 2; ++qt) { mred[w][qt][c] = m[qt]; lred[w][qt][c] = l[qt]; }
    }
    if (w > 0) {
#pragma unroll
        for (int dt = 0; dt < 2; ++dt)
#pragma unroll
            for (int qt = 0; qt < 2; ++qt)
                *(f32x4*)&Osh[w - 1][dt][qt][lane][0] = acc_o[dt][qt];
    }
    __syncthreads();
    if (w == 0) {
#pragma unroll
        for (int qt = 0; qt < 2; ++qt) {
            float m0_ = mred[0][qt][c], m1_ = mred[1][qt][c];
            float m2_ = mred[2][qt][c], m3_ = mred[3][qt][c];
            float M = fmaxf(fmaxf(m0_, m1_), fmaxf(m2_, m3_));
            float a0 = __expf(m0_ - M), a1 = __expf(m1_ - M);
            float a2 = __expf(m2_ - M), a3 = __expf(m3_ - M);
            float L = a0 * lred[0][qt][c] + a1 * lred[1][qt][c]
                    + a2 * lred[2][qt][c] + a3 * lred[3][qt][c];
            float inv = 1.f / L;
#pragma unroll
            for (int dt = 0; dt < 2; ++dt) {
                f32x4 o1 = *(const f32x4*)&Osh[0][dt][qt][lane][0];
                f32x4 o2 = *(const f32x4*)&Osh[1][dt][qt][lane][0];
                f32x4 o3 = *(const f32x4*)&Osh[2][dt][qt][lane][0];
                float4 r;
                r.x = (acc_o[dt][qt][0] * a0 + o1[0] * a1 + o2[0] * a2 + o3[0] * a3) * inv;
                r.y = (acc_o[dt][qt][1] * a0 + o1[1] * a1 + o2[1] * a2 + o3[1] * a3) * inv;
                r.z = (acc_o[dt][qt][2] * a0 + o1[2] * a1 + o2[2] * a2 + o3[2] * a3) * inv;
                r.w = (acc_o[dt][qt][3] * a0 + o1[3] * a1 + o2[3] * a2 + o3[3] * a3) * inv;
                *(float4*)(O + (qbase + qt * 16 + c) * ldo + h * HD + dt * 16 + 4 * g) = r;
            }
        }
    }
}

// ---------------------------------------------------------------------------
// MFMA local windowed attention (verified; strides + fused id-gating)
// ---------------------------------------------------------------------------
__global__ __launch_bounds__(256, 1) void local_mfma(const float* __restrict__ Q, int ldq,
                                                     const float* __restrict__ K, int ldk,
                                                     const float* __restrict__ V, int ldv,
                                                     const float* __restrict__ idkv,
                                                     float* __restrict__ O, int ldo) {
    __shared__ unsigned short Kp[768 * 40];
    __shared__ unsigned short Vt[32 * 776];
    __shared__ float mred[4][3][16];
    __shared__ float lred[4][3][16];
    __shared__ float Osh[3][2][3][64][4];
    int y = blockIdx.x, h = blockIdx.y;
    int tid = threadIdx.x;
    int w = tid >> 6, lane = tid & 63;
    int g = lane >> 4, c = lane & 15;

#pragma unroll 4
    for (int rep = 0; rep < 24; ++rep) {
        int idx = rep * 256 + tid;
        int key = idx >> 3, dq = idx & 7;
        int ky = key / 48;
        int xx = key - 48 * ky;
        int yy = y + ky - 7;
        bool ok = (xx < 40) && (yy >= 0) && (yy < 40);
        float4 fk = make_float4(0.f, 0.f, 0.f, 0.f);
        float4 fv = make_float4(0.f, 0.f, 0.f, 0.f);
        if (ok) {
            int row = yy * 40 + xx;
            fk = *(const float4*)(K + row * ldk + h * HD + 4 * dq);
            fv = *(const float4*)(V + row * ldv + h * HD + 4 * dq);
            if (idkv) {
                float gt = 1.f + tanhf(idkv[row * 264 + h]);
                fk.x *= gt; fk.y *= gt; fk.z *= gt; fk.w *= gt;
                float4 av = *(const float4*)(idkv + row * 264 + 8 + h * HD + 4 * dq);
                fv.x += av.x; fv.y += av.y; fv.z += av.z; fv.w += av.w;
            }
        }
        *(uint2*)&Kp[key * 40 + 4 * dq] = make_uint2(pkbf(fk.x, fk.y), pkbf(fk.z, fk.w));
        int vb = (4 * dq) * 776 + key;
        Vt[vb] = f2bf(fv.x);
        Vt[vb + 776] = f2bf(fv.y);
        Vt[vb + 1552] = f2bf(fv.z);
        Vt[vb + 2328] = f2bf(fv.w);
    }

    short8 qfrag[3];
#pragma unroll
    for (int qt = 0; qt < 3; ++qt) {
        short8 s = { 0, 0, 0, 0, 0, 0, 0, 0 };
        int qx = qt * 16 + c;
        if (qx < 40) {
            const float* qp = Q + (y * 40 + qx) * ldq + h * HD + g * 8;
            float4 f0 = *(const float4*)qp;
            float4 f1 = *(const float4*)(qp + 4);
            s[0] = (short)f2bf(f0.x * SCALE_QK); s[1] = (short)f2bf(f0.y * SCALE_QK);
            s[2] = (short)f2bf(f0.z * SCALE_QK); s[3] = (short)f2bf(f0.w * SCALE_QK);
            s[4] = (short)f2bf(f1.x * SCALE_QK); s[5] = (short)f2bf(f1.y * SCALE_QK);
            s[6] = (short)f2bf(f1.z * SCALE_QK); s[7] = (short)f2bf(f1.w * SCALE_QK);
        }
        qfrag[qt] = s;
    }
    __syncthreads();

    f32x4 sfr[12][3];
    const f32x4 zf = { 0.f, 0.f, 0.f, 0.f };
#pragma unroll
    for (int i = 0; i < 12; ++i) {
        int ky = 4 * w + i / 3;
        int fx = i % 3;
        short8 kf = *(const short8*)&Kp[(ky * 48 + fx * 16 + c) * 40 + 8 * g];
#pragma unroll
        for (int qt = 0; qt < 3; ++qt)
            sfr[i][qt] = __builtin_amdgcn_mfma_f32_16x16x32_bf16(kf, qfrag[qt], zf, 0, 0, 0);
    }

    float mw[3] = { -1e30f, -1e30f, -1e30f };
#pragma unroll
    for (int i = 0; i < 12; ++i) {
        int ky = 4 * w + i / 3, fx = i % 3;
        int yy = y + ky - 7;
        bool rowok = (yy >= 0) && (yy < 40);
        int xxb = fx * 16 + 4 * g;
#pragma unroll
        for (int qt = 0; qt < 3; ++qt) {
            int qx = qt * 16 + c;
#pragma unroll
            for (int r = 0; r < 4; ++r) {
                int xx = xxb + r;
                int dd = xx - qx;
                bool ok = rowok && (xx < 40) && (dd <= 7) && (dd >= -7);
                float v = ok ? sfr[i][qt][r] : -1e9f;
                sfr[i][qt][r] = v;
                mw[qt] = fmaxf(mw[qt], v);
            }
        }
    }
#pragma unroll
    for (int qt = 0; qt < 3; ++qt) {
        mw[qt] = fmaxf(mw[qt], __shfl_xor(mw[qt], 16, 64));
        mw[qt] = fmaxf(mw[qt], __shfl_xor(mw[qt], 32, 64));
    }
    if (lane < 16) {
#pragma unroll
        for (int qt = 0; qt < 3; ++qt) mred[w][qt][lane] = mw[qt];
    }
    __syncthreads();
    float M[3];
#pragma unroll
    for (int qt = 0; qt < 3; ++qt)
        M[qt] = fmaxf(fmaxf(mred[0][qt][c], mred[1][qt][c]),
                      fmaxf(mred[2][qt][c], mred[3][qt][c]));

    float lsum[3] = { 0.f, 0.f, 0.f };
    f32x4 acc_o[2][3] = {};
    int src_lo = 16 * ((2 * g) & 3) + c;
    int src_hi = 16 * ((2 * g + 1) & 3) + c;
    bool hisel = (g >= 2);
#pragma unroll
    for (int chk = 0; chk < 6; ++chk) {
        short8 pfrag[3];
#pragma unroll
        for (int qt = 0; qt < 3; ++qt) {
            float p00 = __expf(sfr[2 * chk][qt][0] - M[qt]);
            float p01 = __expf(sfr[2 * chk][qt][1] - M[qt]);
            float p02 = __expf(sfr[2 * chk][qt][2] - M[qt]);
            float p03 = __expf(sfr[2 * chk][qt][3] - M[qt]);
            float p10 = __expf(sfr[2 * chk + 1][qt][0] - M[qt]);
            float p11 = __expf(sfr[2 * chk + 1][qt][1] - M[qt]);
            float p12 = __expf(sfr[2 * chk + 1][qt][2] - M[qt]);
            float p13 = __expf(sfr[2 * chk + 1][qt][3] - M[qt]);
            lsum[qt] += ((p00 + p01) + (p02 + p03)) + ((p10 + p11) + (p12 + p13));
            unsigned w00 = pkbf(p00, p01), w01 = pkbf(p02, p03);
            unsigned w10 = pkbf(p10, p11), w11 = pkbf(p12, p13);
            unsigned a0 = __shfl(w00, src_lo, 64);
            unsigned a1 = __shfl(w10, src_lo, 64);
            unsigned b0 = __shfl(w01, src_lo, 64);
            unsigned b1 = __shfl(w11, src_lo, 64);
            unsigned c0 = __shfl(w00, src_hi, 64);
            unsigned c1 = __shfl(w10, src_hi, 64);
            unsigned d0 = __shfl(w01, src_hi, 64);
            unsigned d1 = __shfl(w11, src_hi, 64);
            union { short8 s8; unsigned u[4]; } P;
            P.u[0] = hisel ? a1 : a0;
            P.u[1] = hisel ? b1 : b0;
            P.u[2] = hisel ? c1 : c0;
            P.u[3] = hisel ? d1 : d0;
            pfrag[qt] = P.s8;
        }
        int jb = 32 * (6 * w + chk);
        short8 vf0 = *(const short8*)&Vt[c * 776 + jb + 8 * g];
        short8 vf1 = *(const short8*)&Vt[(16 + c) * 776 + jb + 8 * g];
#pragma unroll
        for (int qt = 0; qt < 3; ++qt) {
            acc_o[0][qt] = __builtin_amdgcn_mfma_f32_16x16x32_bf16(vf0, pfrag[qt], acc_o[0][qt], 0, 0, 0);
            acc_o[1][qt] = __builtin_amdgcn_mfma_f32_16x16x32_bf16(vf1, pfrag[qt], acc_o[1][qt], 0, 0, 0);
        }
    }

#pragma unroll
    for (int qt = 0; qt < 3; ++qt) {
        lsum[qt] += __shfl_xor(lsum[qt], 16, 64);
        lsum[qt] += __shfl_xor(lsum[qt], 32, 64);
    }
    if (lane < 16) {
#pragma unroll
        for (int qt = 0; qt < 3; ++qt) lred[w][qt][lane] = lsum[qt];
    }
    if (w > 0) {
#pragma unroll
        for (int dt = 0; dt < 2; ++dt)
#pragma unroll
            for (int qt = 0; qt < 3; ++qt)
                *(f32x4*)&Osh[w - 1][dt][qt][lane][0] = acc_o[dt][qt];
    }
    __syncthreads();
    if (w == 0) {
#pragma unroll
        for (int qt = 0; qt < 3; ++qt) {
            int qx = qt * 16 + c;
            if (qx >= 40) continue;
            float L = (lred[0][qt][c] + lred[1][qt][c]) + (lred[2][qt][c] + lred[3][qt][c]);
            float inv = 1.f / L;
#pragma unroll
            for (int dt = 0; dt < 2; ++dt) {
                f32x4 o1 = *(const f32x4*)&Osh[0][dt][qt][lane][0];
                f32x4 o2 = *(const f32x4*)&Osh[1][dt][qt][lane][0];
                f32x4 o3 = *(const f32x4*)&Osh[2][dt][qt][lane][0];
                float4 r;
                r.x = (acc_o[dt][qt][0] + o1[0] + o2[0] + o3[0]) * inv;
                r.y = (acc_o[dt][qt][1] + o1[1] + o2[1] + o3[1]) * inv;
                r.z = (acc_o[dt][qt][2] + o1[2] + o2[2] + o3[2]) * inv;
                r.w = (acc_o[dt][qt][3] + o1[3] + o2[3] + o3[3]) * inv;
                *(float4*)(O + (y * 40 + qx) * ldo + h * HD + dt * 16 + 4 * g) = r;
            }
        }
    }
}

// merged prep: dw_k transpose + [lt|st] weight concat + bias sum
__global__ __launch_bounds__(256) void prep_misc(const float* __restrict__ Kw,
                                                 const float* __restrict__ lt_wo,
                                                 const float* __restrict__ lt_bo,
                                                 const float* __restrict__ st_wo,
                                                 const float* __restrict__ st_bo,
                                                 float* __restrict__ Kt,
                                                 float* __restrict__ wcat,
                                                 float* __restrict__ bsum) {
    int idx = blockIdx.x * 256 + threadIdx.x;   // 0..65535
    int n = idx >> 8, k = idx & 255;
    wcat[n * 512 + k] = lt_wo[idx];
    wcat[n * 512 + 256 + k] = st_wo[idx];
    if (idx < 256) bsum[idx] = lt_bo[idx] + st_bo[idx];
    if (idx < 25 * DFF_) {
        int kk = idx >> 10, c = idx & 1023;
        Kt[idx] = Kw[c * 25 + kk];
    }
}

// GroupNorm partials: grid (32 groups, 8 chunks); deterministic partial sums.
__global__ __launch_bounds__(256) void gn_partial(const float* __restrict__ X,
                                                  float* __restrict__ gstat) {
    __shared__ float sh4[4];
    int g = blockIdx.x, chunk = blockIdx.y;
    int base = g * 32;
    float s = 0.f, s2 = 0.f;
    for (int i = threadIdx.x; i < 200 * 32; i += 256) {
        int l = chunk * 200 + (i >> 5), c = i & 31;
        float v = X[l * DFF_ + base + c];
        s += v;
        s2 += v * v;
    }
    s = blockReduceSum(s, sh4);
    s2 = blockReduceSum(s2, sh4);
    if (threadIdx.x == 0) {
        gstat[g * 8 + chunk] = s;
        gstat[256 + g * 8 + chunk] = s2;
    }
}

// GroupNorm apply + exact GELU, float4-vectorized.
__global__ __launch_bounds__(256) void gn_apply(const float* __restrict__ X,
                                                const float* __restrict__ gstat,
                                                const float* __restrict__ g,
                                                const float* __restrict__ b,
                                                float* __restrict__ Y) {
    int idx = blockIdx.x * 256 + threadIdx.x;
    int e4 = idx * 4;
    int c = e4 & 1023;
    int grp = c >> 5;
    float s = 0.f, s2 = 0.f;
#pragma unroll
    for (int i = 0; i < 8; ++i) {
        s += gstat[grp * 8 + i];
        s2 += gstat[256 + grp * 8 + i];
    }
    const float invn = 1.0f / 51200.f;
    float mean = s * invn;
    float rs = rsqrtf(s2 * invn - mean * mean + 1e-5f);
    float4 v = *(const float4*)(X + e4);
    float4 gg = *(const float4*)(g + c);
    float4 bb = *(const float4*)(b + c);
    float4 r;
    float y0 = (v.x - mean) * rs * gg.x + bb.x;
    float y1 = (v.y - mean) * rs * gg.y + bb.y;
    float y2 = (v.z - mean) * rs * gg.z + bb.z;
    float y3 = (v.w - mean) * rs * gg.w + bb.w;
    r.x = 0.5f * y0 * (1.0f + erff(y0 * 0.70710678118654752f));
    r.y = 0.5f * y1 * (1.0f + erff(y1 * 0.70710678118654752f));
    r.z = 0.5f * y2 * (1.0f + erff(y2 * 0.70710678118654752f));
    r.w = 0.5f * y3 * (1.0f + erff(y3 * 0.70710678118654752f));
    *(float4*)(Y + e4) = r;
}

// depthwise 5x5 conv v2 (verified)
__global__ __launch_bounds__(256) void dwconv_v2(const float* __restrict__ X,
                                                 const float* __restrict__ Kt,
                                                 float* __restrict__ Y) {
    int l = blockIdx.x;
    int c4 = threadIdx.x * 4;
    int y = l / GRID_W, x = l - y * GRID_W;
    float4 acc = make_float4(0.f, 0.f, 0.f, 0.f);
    if (y >= 2 && y < GRID_H - 2 && x >= 2 && x < GRID_W - 2) {
#pragma unroll
        for (int ky = 0; ky < 5; ++ky) {
#pragma unroll
            for (int kx = 0; kx < 5; ++kx) {
                float4 xv = *(const float4*)(X + ((y + ky - 2) * GRID_W + x + kx - 2) * DFF_ + c4);
                float4 wv = *(const float4*)(Kt + (ky * 5 + kx) * DFF_ + c4);
                acc.x += xv.x * wv.x; acc.y += xv.y * wv.y;
                acc.z += xv.z * wv.z; acc.w += xv.w * wv.w;
            }
        }
    } else {
#pragma unroll
        for (int ky = 0; ky < 5; ++ky) {
            int yy = y + ky - 2;
            if (yy < 0 || yy >= GRID_H) continue;
#pragma unroll
            for (int kx = 0; kx < 5; ++kx) {
                int xx = x + kx - 2;
                if (xx < 0 || xx >= GRID_W) continue;
                float4 xv = *(const float4*)(X + (yy * GRID_W + xx) * DFF_ + c4);
                float4 wv = *(const float4*)(Kt + (ky * 5 + kx) * DFF_ + c4);
                acc.x += xv.x * wv.x; acc.y += xv.y * wv.y;
                acc.z += xv.z * wv.z; acc.w += xv.w * wv.w;
            }
        }
    }
    *(float4*)(Y + l * DFF_ + c4) = acc;
}

extern "C" void kernel_launch(void* const* d_in, const int* in_sizes, int n_in,
                              void* d_out, int out_size, void* d_ws, size_t ws_size,
                              hipStream_t stream) {
    (void)in_sizes; (void)n_in; (void)out_size; (void)ws_size;
    const float* tgt = (const float*)d_in[0];
    const float* curr_id_emb = (const float*)d_in[1];
    const float* self_pos = (const float*)d_in[2];
    const float* ln1_g = (const float*)d_in[3];
    const float* ln1_b = (const float*)d_in[4];
    const float* sa_wq = (const float*)d_in[5];
    const float* sa_bq = (const float*)d_in[6];
    const float* sa_wk = (const float*)d_in[7];
    const float* sa_bk = (const float*)d_in[8];
    const float* sa_wv = (const float*)d_in[9];
    const float* sa_bv = (const float*)d_in[10];
    const float* sa_wo = (const float*)d_in[11];
    const float* sa_bo = (const float*)d_in[12];
    const float* ln2_g = (const float*)d_in[13];
    const float* ln2_b = (const float*)d_in[14];
    const float* w_qv = (const float*)d_in[15];
    const float* b_qv = (const float*)d_in[16];
    const float* w_id = (const float*)d_in[17];
    const float* b_id = (const float*)d_in[18];
    const float* lt_wo = (const float*)d_in[19];
    const float* lt_bo = (const float*)d_in[20];
    const float* st_wo = (const float*)d_in[21];
    const float* st_bo = (const float*)d_in[22];
    const float* ln3_g = (const float*)d_in[23];
    const float* ln3_b = (const float*)d_in[24];
    const float* w1 = (const float*)d_in[25];
    const float* b1 = (const float*)d_in[26];
    const float* gn_g = (const float*)d_in[27];
    const float* gn_b = (const float*)d_in[28];
    const float* dw_k = (const float*)d_in[29];
    const float* w2 = (const float*)d_in[30];
    const float* b2 = (const float*)d_in[31];
    float* out = (float*)d_out;

    float* ws = (float*)d_ws;
    const int LC = L_SEQ * CDIM;           // 409600
    float* bufA = ws;                      // ln outputs
    float* bufB = bufA + LC;               // qk_in / tgt_b
    float* bufC = bufB + LC;               // q_
    float* bufD = bufC + LC;               // k_
    float* bufE = bufD + LC;               // v_
    float* bufG = bufE + LC;               // tgt1
    float* bufFW = bufG + LC;              // attn outs (1600x512)
    float* bufH = bufFW + L_SEQ * 512;     // qv (1600x512); later gstat
    float* bufI = bufH + L_SEQ * 512;      // idkv (1600x264)
    float* bufX = bufI + L_SEQ * 264;      // w1 out (1600x1024)
    float* bufY = bufX + L_SEQ * DFF_;     // gn+gelu out
    float* bufZ = bufY + L_SEQ * DFF_;     // conv out
    float* bufW = bufZ + L_SEQ * DFF_;     // transposed dw_k (25x1024)
    float* wcat = bufW + 25 * DFF_;        // concat lt/st weights (256x512)
    float* bsum = wcat + 256 * 512;        // summed biases (256)

    dim3 blk(256);
    dim3 mhaGrid(L_SEQ / QBLK, NH);        // (50, 8)
    auto J = [](const float* A, const float* W, const float* bias, const float* res,
                float* C, int N, int K) {
        GJob j; j.A = A; j.W = W; j.bias = bias; j.res = res; j.C = C; j.N = N; j.K = K;
        return j;
    };

    // 0. merged prep (independent)
    prep_misc<<<256, blk, 0, stream>>>(dw_k, lt_wo, lt_bo, st_wo, st_bo, bufW, wcat, bsum);
    // 1. LN1: bufA = ln(tgt), bufB = bufA + self_pos
    ln_kernel<<<L_SEQ, blk, 0, stream>>>(tgt, ln1_g, ln1_b, self_pos, bufA, bufB);
    // 2. q,k,v projections (one batched dispatch, 300 blocks)
    {
        GJob jq = J(bufB, sa_wq, sa_bq, nullptr, bufC, CDIM, CDIM);
        GJob jk = J(bufB, sa_wk, sa_bk, nullptr, bufD, CDIM, CDIM);
        GJob jv = J(bufA, sa_wv, sa_bv, nullptr, bufE, CDIM, CDIM);
        gemm_mfma<<<dim3(4, 25, 3), blk, 0, stream>>>(jq, jk, jv);
    }
    // 3. self attention -> bufFW (ldo=256)
    mha_mfma<<<mhaGrid, blk, 0, stream>>>(bufC, CDIM, bufD, CDIM, bufE, CDIM, nullptr, bufFW, CDIM);
    // 4. out proj + residual -> tgt1 (bufG)
    {
        GJob jo = J(bufFW, sa_wo, sa_bo, tgt, bufG, CDIM, CDIM);
        gemm_mfma<<<dim3(4, 25, 1), blk, 0, stream>>>(jo, jo, jo);
    }
    // 5. LN2 -> bufA
    ln_kernel<<<L_SEQ, blk, 0, stream>>>(bufG, ln2_g, ln2_b, nullptr, bufA, nullptr);
    // 6. qv + idkv (one batched dispatch)
    {
        GJob jqv = J(bufA, w_qv, b_qv, nullptr, bufH, 512, CDIM);
        GJob jid = J(curr_id_emb, w_id, b_id, nullptr, bufI, 264, CDIM);
        gemm_mfma<<<dim3(8, 25, 2), blk, 0, stream>>>(jqv, jid, jid);
    }
    // 7. long-term attention (gating fused) -> bufFW cols 0..255
    mha_mfma<<<mhaGrid, blk, 0, stream>>>(bufH, 512, bufH, 512, bufH + 256, 512, bufI, bufFW, 512);
    // 8. local attention (gating fused) -> bufFW cols 256..511
    local_mfma<<<dim3(GRID_H, NH), blk, 0, stream>>>(bufH, 512, bufH, 512, bufH + 256, 512, bufI, bufFW + 256, 512);
    // 9. merged lt/st projection: tgt_b = tgt1 + [mha2|local] @ wcat^T + bsum -> bufB
    {
        GJob jm = J(bufFW, wcat, bsum, bufG, bufB, CDIM, 512);
        gemm_mfma<<<dim3(4, 25, 1), blk, 0, stream>>>(jm, jm, jm);
    }
    // 10. LN3 -> bufA
    ln_kernel<<<L_SEQ, blk, 0, stream>>>(bufB, ln3_g, ln3_b, nullptr, bufA, nullptr);
    // 11. x = bufA @ w1^T -> bufX
    {
        GJob jw1 = J(bufA, w1, b1, nullptr, bufX, DFF_, CDIM);
        gemm_mfma<<<dim3(16, 25, 1), blk, 0, stream>>>(jw1, jw1, jw1);
    }
    // 12. GroupNorm + GELU -> bufY (bufH dead; reuse as gstat)
    gn_partial<<<dim3(32, 8), blk, 0, stream>>>(bufX, bufH);
    gn_apply<<<L_SEQ, blk, 0, stream>>>(bufX, bufH, gn_g, gn_b, bufY);
    // 13. depthwise conv -> bufZ
    dwconv_v2<<<L_SEQ, blk, 0, stream>>>(bufY, bufW, bufZ);
    // 14. final proj + residual(tgt_b) -> out
    {
        GJob jw2 = J(bufZ, w2, b2, bufB, out, CDIM, DFF_);
        gemm_mfma<<<dim3(4, 25, 1), blk, 0, stream>>>(jw2, jw2, jw2);
    }
}

// Round 12
// 354.893 us; speedup vs baseline: 1.0927x; 1.0637x over previous
//
#include <hip/hip_runtime.h>
#include <math.h>

#define L_SEQ 1600
#define CDIM 256
#define NH 8
#define HD 32
#define GRID_H 40
#define GRID_W 40
#define DFF_ 1024
#define SCALE_QK 0.17677669529663687f
#define NTILE 13   // ceil(1600/128)

typedef __attribute__((ext_vector_type(8))) short short8;
typedef __attribute__((ext_vector_type(4))) float f32x4;

__device__ __forceinline__ float waveReduceSum(float v) {
#pragma unroll
    for (int off = 32; off > 0; off >>= 1) v += __shfl_down(v, off, 64);
    return v;
}
__device__ __forceinline__ float blockReduceSum(float v, float* sh4) {
    v = waveReduceSum(v);
    int lane = threadIdx.x & 63, wid = threadIdx.x >> 6;
    __syncthreads();
    if (lane == 0) sh4[wid] = v;
    __syncthreads();
    return sh4[0] + sh4[1] + sh4[2] + sh4[3];
}

__device__ __forceinline__ unsigned short f2bf(float x) {
    union { float f; unsigned u; } v; v.f = x;
    unsigned r = (v.u + 0x7FFFu + ((v.u >> 16) & 1u)) >> 16;
    return (unsigned short)r;
}
__device__ __forceinline__ unsigned pkbf(float lo, float hi) {
    return (unsigned)f2bf(lo) | ((unsigned)f2bf(hi) << 16);
}

// LayerNorm over C=256; one block per row. out2 = out + addin (optional)
__global__ __launch_bounds__(256) void ln_kernel(const float* __restrict__ x,
                                                 const float* __restrict__ g,
                                                 const float* __restrict__ b,
                                                 const float* __restrict__ addin,
                                                 float* __restrict__ out,
                                                 float* __restrict__ out2) {
    __shared__ float sh4[4];
    int row = blockIdx.x;
    int c = threadIdx.x;
    float v = x[row * CDIM + c];
    float mean = blockReduceSum(v, sh4) * (1.0f / CDIM);
    float d = v - mean;
    float var = blockReduceSum(d * d, sh4) * (1.0f / CDIM);
    float y = d * rsqrtf(var + 1e-5f) * g[c] + b[c];
    out[row * CDIM + c] = y;
    if (out2) out2[row * CDIM + c] = y + addin[row * CDIM + c];
}

// ---------------------------------------------------------------------------
// bf16 MFMA GEMM, batched up to 3 jobs via blockIdx.z (verified body).
// ---------------------------------------------------------------------------
struct GJob {
    const float* A; const float* W; const float* bias; const float* res;
    float* C; int N; int K;
};

__global__ __launch_bounds__(256) void gemm_mfma(GJob j0, GJob j1, GJob j2) {
    GJob j = j0;
    if (blockIdx.z == 1) j = j1;
    else if (blockIdx.z == 2) j = j2;
    const float* __restrict__ A = j.A;
    const float* __restrict__ W = j.W;
    const float* bias = j.bias;
    const float* res = j.res;
    float* __restrict__ C = j.C;
    int N = j.N, K = j.K;

    __shared__ unsigned short Al[2][4][64][8];
    __shared__ unsigned short Bl[2][4][64][8];
    int tid = threadIdx.x;
    int bm = blockIdx.y * 64, bn = blockIdx.x * 64;
    if (bn >= N) return;
    int lane = tid & 63, wave = tid >> 6;
    int wr = wave >> 1, wc = wave & 1;

    int srow = tid >> 3;
    int q = tid & 7;
    int e0 = (q & 1) * 4;

    f32x4 acc[2][2] = {};
    int nsteps = K >> 5;

    float4 ra[2], rb[2];
    {
#pragma unroll
        for (int r = 0; r < 2; ++r) {
            int row = srow + 32 * r;
            ra[r] = *(const float4*)(A + (bm + row) * K + 4 * q);
            int n = bn + row;
            rb[r] = (n < N) ? *(const float4*)(W + n * K + 4 * q)
                            : make_float4(0.f, 0.f, 0.f, 0.f);
        }
#pragma unroll
        for (int r = 0; r < 2; ++r) {
            int row = srow + 32 * r;
            int frag = (row >> 4), l = (row & 15) + 16 * (q >> 1);
            *(uint2*)&Al[0][frag][l][e0] = make_uint2(pkbf(ra[r].x, ra[r].y), pkbf(ra[r].z, ra[r].w));
            *(uint2*)&Bl[0][frag][l][e0] = make_uint2(pkbf(rb[r].x, rb[r].y), pkbf(rb[r].z, rb[r].w));
        }
    }
    __syncthreads();

    for (int s = 0; s < nsteps; ++s) {
        bool more = (s + 1) < nsteps;
        if (more) {
            int k0 = (s + 1) << 5;
#pragma unroll
            for (int r = 0; r < 2; ++r) {
                int row = srow + 32 * r;
                ra[r] = *(const float4*)(A + (bm + row) * K + k0 + 4 * q);
                int n = bn + row;
                rb[r] = (n < N) ? *(const float4*)(W + n * K + k0 + 4 * q)
                                : make_float4(0.f, 0.f, 0.f, 0.f);
            }
        }
        {
            int buf = s & 1;
            short8 af[2], bfr[2];
#pragma unroll
            for (int i = 0; i < 2; ++i) {
                af[i] = *(const short8*)&Al[buf][2 * wr + i][lane][0];
                bfr[i] = *(const short8*)&Bl[buf][2 * wc + i][lane][0];
            }
#pragma unroll
            for (int i = 0; i < 2; ++i)
#pragma unroll
                for (int jj = 0; jj < 2; ++jj)
                    acc[i][jj] = __builtin_amdgcn_mfma_f32_16x16x32_bf16(af[i], bfr[jj], acc[i][jj], 0, 0, 0);
        }
        if (more) {
            int buf = (s + 1) & 1;
#pragma unroll
            for (int r = 0; r < 2; ++r) {
                int row = srow + 32 * r;
                int frag = (row >> 4), l = (row & 15) + 16 * (q >> 1);
                *(uint2*)&Al[buf][frag][l][e0] = make_uint2(pkbf(ra[r].x, ra[r].y), pkbf(ra[r].z, ra[r].w));
                *(uint2*)&Bl[buf][frag][l][e0] = make_uint2(pkbf(rb[r].x, rb[r].y), pkbf(rb[r].z, rb[r].w));
            }
        }
        __syncthreads();
    }

#pragma unroll
    for (int jj = 0; jj < 2; ++jj) {
        int col = bn + wc * 32 + jj * 16 + (lane & 15);
        if (col >= N) continue;
        float bv = bias ? bias[col] : 0.f;
#pragma unroll
        for (int i = 0; i < 2; ++i) {
            int rbase = bm + wr * 32 + i * 16 + ((lane >> 4) << 2);
#pragma unroll
            for (int r = 0; r < 4; ++r) {
                int row = rbase + r;
                float v = acc[i][jj][r] + bv;
                if (res) v += res[row * N + col];
                C[row * N + col] = v;
            }
        }
    }
}

// ---------------------------------------------------------------------------
// prep_kv: build bf16 fragment-layout K/V tiles per (head, 128-key tile),
// with optional id-gating. Replicates mha staging math exactly.
// Kf tile = 4096 shorts ([8][64][8]); Vf tile = 6144 shorts ([4][2][64][12]).
// ---------------------------------------------------------------------------
#define KTJ 128
__global__ __launch_bounds__(256) void prep_kv(const float* __restrict__ K, int ldk,
                                               const float* __restrict__ V, int ldv,
                                               const float* __restrict__ idkv,
                                               unsigned short* __restrict__ Kf,
                                               unsigned short* __restrict__ Vf) {
    int tile = blockIdx.x, h = blockIdx.y;
    int t = tile * KTJ;
    int tid = threadIdx.x;
    unsigned short* kb = Kf + (h * NTILE + tile) * 4096;
    unsigned short* vb = Vf + (h * NTILE + tile) * 6144;
    // ---- K fragment (gated) ----
    {
        int jrow = tid >> 1;
        int dhalf = (tid & 1) * 16;
        int jj = t + jrow;
        float4 f0, f1, f2, f3;
        if (jj < L_SEQ) {
            const float4* kp = (const float4*)(K + jj * ldk + h * HD + dhalf);
            f0 = kp[0]; f1 = kp[1]; f2 = kp[2]; f3 = kp[3];
            if (idkv) {
                float gt = 1.f + tanhf(idkv[jj * 264 + h]);
                f0.x *= gt; f0.y *= gt; f0.z *= gt; f0.w *= gt;
                f1.x *= gt; f1.y *= gt; f1.z *= gt; f1.w *= gt;
                f2.x *= gt; f2.y *= gt; f2.z *= gt; f2.w *= gt;
                f3.x *= gt; f3.y *= gt; f3.z *= gt; f3.w *= gt;
            }
        } else {
            f0 = f1 = f2 = f3 = make_float4(0.f, 0.f, 0.f, 0.f);
        }
        int jt = jrow >> 4;
        int laneA = (jrow & 15) + dhalf * 2;
        short8 s0, s1;
        s0[0]=f2bf(f0.x); s0[1]=f2bf(f0.y); s0[2]=f2bf(f0.z); s0[3]=f2bf(f0.w);
        s0[4]=f2bf(f1.x); s0[5]=f2bf(f1.y); s0[6]=f2bf(f1.z); s0[7]=f2bf(f1.w);
        s1[0]=f2bf(f2.x); s1[1]=f2bf(f2.y); s1[2]=f2bf(f2.z); s1[3]=f2bf(f2.w);
        s1[4]=f2bf(f3.x); s1[5]=f2bf(f3.y); s1[6]=f2bf(f3.z); s1[7]=f2bf(f3.w);
        *(short8*)&kb[(jt * 64 + laneA) * 8] = s0;
        *(short8*)&kb[(jt * 64 + laneA + 16) * 8] = s1;
    }
    // ---- V fragment (transposed, +id_v) ----
    {
        int vjq = tid >> 3, vdq = tid & 7;
        int vjr = 4 * vjq, vd0 = 4 * vdq;
        int vjc = vjr >> 5, vdt = vd0 >> 4, vjg = (vjr & 31) >> 3, ve0 = vjr & 7;
        float4 rr[4];
        int j0 = t + vjr;
#pragma unroll
        for (int r = 0; r < 4; ++r) {
            int jj = j0 + r;
            if (jj < L_SEQ) {
                float4 fv = *(const float4*)(V + jj * ldv + h * HD + vd0);
                if (idkv) {
                    float4 av = *(const float4*)(idkv + jj * 264 + 8 + h * HD + vd0);
                    fv.x += av.x; fv.y += av.y; fv.z += av.z; fv.w += av.w;
                }
                rr[r] = fv;
            } else {
                rr[r] = make_float4(0.f, 0.f, 0.f, 0.f);
            }
        }
        float col[4][4] = {
            { rr[0].x, rr[1].x, rr[2].x, rr[3].x },
            { rr[0].y, rr[1].y, rr[2].y, rr[3].y },
            { rr[0].z, rr[1].z, rr[2].z, rr[3].z },
            { rr[0].w, rr[1].w, rr[2].w, rr[3].w } };
#pragma unroll
        for (int dd = 0; dd < 4; ++dd) {
            int laneV = ((vd0 + dd) & 15) + 16 * vjg;
            uint2 pk;
            pk.x = pkbf(col[dd][0], col[dd][1]);
            pk.y = pkbf(col[dd][2], col[dd][3]);
            *(uint2*)&vb[((vjc * 2 + vdt) * 64 + laneV) * 12 + ve0] = pk;
        }
    }
}

// ---------------------------------------------------------------------------
// MFMA flash attention, QBLK=32; K/V read from prebuilt fragment buffers.
// Staging is a pure linear float4 copy (no cvt / gating / transpose).
// ---------------------------------------------------------------------------
#define QBLK 32
__global__ __launch_bounds__(256) void mha_mfma(const float* __restrict__ Q, int ldq,
                                                const unsigned short* __restrict__ Kf,
                                                const unsigned short* __restrict__ Vf,
                                                float* __restrict__ O, int ldo) {
    __shared__ unsigned short Kl[8][64][8];
    __shared__ unsigned short Vl[4][2][64][12];
    __shared__ float mred[4][2][16];
    __shared__ float lred[4][2][16];
    __shared__ float Osh[3][2][2][64][4];
    int h = blockIdx.y;
    int qbase = blockIdx.x * QBLK;
    int tid = threadIdx.x;
    int w = tid >> 6, lane = tid & 63;
    int g = lane >> 4, c = lane & 15;

    short8 qfrag[2];
#pragma unroll
    for (int qt = 0; qt < 2; ++qt) {
        const float* qp = Q + (qbase + qt * 16 + c) * ldq + h * HD + g * 8;
        float4 f0 = *(const float4*)qp;
        float4 f1 = *(const float4*)(qp + 4);
        short8 s;
        s[0] = (short)f2bf(f0.x * SCALE_QK); s[1] = (short)f2bf(f0.y * SCALE_QK);
        s[2] = (short)f2bf(f0.z * SCALE_QK); s[3] = (short)f2bf(f0.w * SCALE_QK);
        s[4] = (short)f2bf(f1.x * SCALE_QK); s[5] = (short)f2bf(f1.y * SCALE_QK);
        s[6] = (short)f2bf(f1.z * SCALE_QK); s[7] = (short)f2bf(f1.w * SCALE_QK);
        qfrag[qt] = s;
    }

    float m[2] = { -INFINITY, -INFINITY };
    float l[2] = { 0.f, 0.f };
    f32x4 acc_o[2][2] = {};

    int src_lo = 16 * ((2 * g) & 3) + c;
    int src_hi = 16 * ((2 * g + 1) & 3) + c;
    bool hisel = (g >= 2);

    const float4* kfb = (const float4*)(Kf + h * NTILE * 4096);
    const float4* vfb = (const float4*)(Vf + h * NTILE * 6144);
    float4* kdst = (float4*)&Kl[0][0][0];
    float4* vdst = (float4*)&Vl[0][0][0][0];

    for (int tile = 0; tile < NTILE; ++tile) {
        int t = tile * KTJ;
        // ---- stage: pure linear copy (512 + 768 float4s) ----
        {
            const float4* ks = kfb + tile * 512;
            const float4* vs = vfb + tile * 768;
            kdst[tid] = ks[tid];
            kdst[tid + 256] = ks[tid + 256];
            vdst[tid] = vs[tid];
            vdst[tid + 256] = vs[tid + 256];
            vdst[tid + 512] = vs[tid + 512];
        }
        __syncthreads();

        bool alive = (t + 32 * w) < L_SEQ;
        if (alive) {
            short8 kf0 = *(const short8*)&Kl[2 * w][lane][0];
            short8 kf1 = *(const short8*)&Kl[2 * w + 1][lane][0];
            f32x4 zero = { 0.f, 0.f, 0.f, 0.f };
            f32x4 s[2][2];
            s[0][0] = __builtin_amdgcn_mfma_f32_16x16x32_bf16(kf0, qfrag[0], zero, 0, 0, 0);
            s[0][1] = __builtin_amdgcn_mfma_f32_16x16x32_bf16(kf0, qfrag[1], zero, 0, 0, 0);
            s[1][0] = __builtin_amdgcn_mfma_f32_16x16x32_bf16(kf1, qfrag[0], zero, 0, 0, 0);
            s[1][1] = __builtin_amdgcn_mfma_f32_16x16x32_bf16(kf1, qfrag[1], zero, 0, 0, 0);

            short8 pfrag[2];
#pragma unroll
            for (int qt = 0; qt < 2; ++qt) {
                float mx = s[0][qt][0];
                mx = fmaxf(mx, s[0][qt][1]); mx = fmaxf(mx, s[0][qt][2]); mx = fmaxf(mx, s[0][qt][3]);
                mx = fmaxf(mx, s[1][qt][0]); mx = fmaxf(mx, s[1][qt][1]);
                mx = fmaxf(mx, s[1][qt][2]); mx = fmaxf(mx, s[1][qt][3]);
                mx = fmaxf(mx, __shfl_xor(mx, 16, 64));
                mx = fmaxf(mx, __shfl_xor(mx, 32, 64));
                float nm = fmaxf(m[qt], mx);
                float alpha = __expf(m[qt] - nm);
                m[qt] = nm;
                float p00 = __expf(s[0][qt][0] - nm), p01 = __expf(s[0][qt][1] - nm);
                float p02 = __expf(s[0][qt][2] - nm), p03 = __expf(s[0][qt][3] - nm);
                float p10 = __expf(s[1][qt][0] - nm), p11 = __expf(s[1][qt][1] - nm);
                float p12 = __expf(s[1][qt][2] - nm), p13 = __expf(s[1][qt][3] - nm);
                float ts = ((p00 + p01) + (p02 + p03)) + ((p10 + p11) + (p12 + p13));
                ts += __shfl_xor(ts, 16, 64);
                ts += __shfl_xor(ts, 32, 64);
                l[qt] = l[qt] * alpha + ts;
#pragma unroll
                for (int dt = 0; dt < 2; ++dt) {
                    acc_o[dt][qt][0] *= alpha; acc_o[dt][qt][1] *= alpha;
                    acc_o[dt][qt][2] *= alpha; acc_o[dt][qt][3] *= alpha;
                }
                unsigned w00 = pkbf(p00, p01), w01 = pkbf(p02, p03);
                unsigned w10 = pkbf(p10, p11), w11 = pkbf(p12, p13);
                unsigned a0 = __shfl(w00, src_lo, 64);
                unsigned a1 = __shfl(w10, src_lo, 64);
                unsigned b0 = __shfl(w01, src_lo, 64);
                unsigned b1 = __shfl(w11, src_lo, 64);
                unsigned c0 = __shfl(w00, src_hi, 64);
                unsigned c1 = __shfl(w10, src_hi, 64);
                unsigned d0 = __shfl(w01, src_hi, 64);
                unsigned d1 = __shfl(w11, src_hi, 64);
                union { short8 s8; unsigned u[4]; } P;
                P.u[0] = hisel ? a1 : a0;
                P.u[1] = hisel ? b1 : b0;
                P.u[2] = hisel ? c1 : c0;
                P.u[3] = hisel ? d1 : d0;
                pfrag[qt] = P.s8;
            }

            union { short8 s8; uint2 v[2]; } vf0u, vf1u;
            vf0u.v[0] = *(const uint2*)&Vl[w][0][lane][0];
            vf0u.v[1] = *(const uint2*)&Vl[w][0][lane][4];
            vf1u.v[0] = *(const uint2*)&Vl[w][1][lane][0];
            vf1u.v[1] = *(const uint2*)&Vl[w][1][lane][4];
            acc_o[0][0] = __builtin_amdgcn_mfma_f32_16x16x32_bf16(vf0u.s8, pfrag[0], acc_o[0][0], 0, 0, 0);
            acc_o[0][1] = __builtin_amdgcn_mfma_f32_16x16x32_bf16(vf0u.s8, pfrag[1], acc_o[0][1], 0, 0, 0);
            acc_o[1][0] = __builtin_amdgcn_mfma_f32_16x16x32_bf16(vf1u.s8, pfrag[0], acc_o[1][0], 0, 0, 0);
            acc_o[1][1] = __builtin_amdgcn_mfma_f32_16x16x32_bf16(vf1u.s8, pfrag[1], acc_o[1][1], 0, 0, 0);
        }
        __syncthreads();
    }

    if (g == 0) {
#pragma unroll
        for (int qt = 0; qt < 2; ++qt) { mred[w][qt][c] = m[qt]; lred[w][qt][c] = l[qt]; }
    }
    if (w > 0) {
#pragma unroll
        for (int dt = 0; dt < 2; ++dt)
#pragma unroll
            for (int qt = 0; qt < 2; ++qt)
                *(f32x4*)&Osh[w - 1][dt][qt][lane][0] = acc_o[dt][qt];
    }
    __syncthreads();
    if (w == 0) {
#pragma unroll
        for (int qt = 0; qt < 2; ++qt) {
            float m0_ = mred[0][qt][c], m1_ = mred[1][qt][c];
            float m2_ = mred[2][qt][c], m3_ = mred[3][qt][c];
            float M = fmaxf(fmaxf(m0_, m1_), fmaxf(m2_, m3_));
            float a0 = __expf(m0_ - M), a1 = __expf(m1_ - M);
            float a2 = __expf(m2_ - M), a3 = __expf(m3_ - M);
            float L = a0 * lred[0][qt][c] + a1 * lred[1][qt][c]
                    + a2 * lred[2][qt][c] + a3 * lred[3][qt][c];
            float inv = 1.f / L;
#pragma unroll
            for (int dt = 0; dt < 2; ++dt) {
                f32x4 o1 = *(const f32x4*)&Osh[0][dt][qt][lane][0];
                f32x4 o2 = *(const f32x4*)&Osh[1][dt][qt][lane][0];
                f32x4 o3 = *(const f32x4*)&Osh[2][dt][qt][lane][0];
                float4 r;
                r.x = (acc_o[dt][qt][0] * a0 + o1[0] * a1 + o2[0] * a2 + o3[0] * a3) * inv;
                r.y = (acc_o[dt][qt][1] * a0 + o1[1] * a1 + o2[1] * a2 + o3[1] * a3) * inv;
                r.z = (acc_o[dt][qt][2] * a0 + o1[2] * a1 + o2[2] * a2 + o3[2] * a3) * inv;
                r.w = (acc_o[dt][qt][3] * a0 + o1[3] * a1 + o2[3] * a2 + o3[3] * a3) * inv;
                *(float4*)(O + (qbase + qt * 16 + c) * ldo + h * HD + dt * 16 + 4 * g) = r;
            }
        }
    }
}

// ---------------------------------------------------------------------------
// MFMA local windowed attention (verified; strides + fused id-gating)
// ---------------------------------------------------------------------------
__global__ __launch_bounds__(256, 1) void local_mfma(const float* __restrict__ Q, int ldq,
                                                     const float* __restrict__ K, int ldk,
                                                     const float* __restrict__ V, int ldv,
                                                     const float* __restrict__ idkv,
                                                     float* __restrict__ O, int ldo) {
    __shared__ unsigned short Kp[768 * 40];
    __shared__ unsigned short Vt[32 * 776];
    __shared__ float mred[4][3][16];
    __shared__ float lred[4][3][16];
    __shared__ float Osh[3][2][3][64][4];
    int y = blockIdx.x, h = blockIdx.y;
    int tid = threadIdx.x;
    int w = tid >> 6, lane = tid & 63;
    int g = lane >> 4, c = lane & 15;

#pragma unroll 4
    for (int rep = 0; rep < 24; ++rep) {
        int idx = rep * 256 + tid;
        int key = idx >> 3, dq = idx & 7;
        int ky = key / 48;
        int xx = key - 48 * ky;
        int yy = y + ky - 7;
        bool ok = (xx < 40) && (yy >= 0) && (yy < 40);
        float4 fk = make_float4(0.f, 0.f, 0.f, 0.f);
        float4 fv = make_float4(0.f, 0.f, 0.f, 0.f);
        if (ok) {
            int row = yy * 40 + xx;
            fk = *(const float4*)(K + row * ldk + h * HD + 4 * dq);
            fv = *(const float4*)(V + row * ldv + h * HD + 4 * dq);
            if (idkv) {
                float gt = 1.f + tanhf(idkv[row * 264 + h]);
                fk.x *= gt; fk.y *= gt; fk.z *= gt; fk.w *= gt;
                float4 av = *(const float4*)(idkv + row * 264 + 8 + h * HD + 4 * dq);
                fv.x += av.x; fv.y += av.y; fv.z += av.z; fv.w += av.w;
            }
        }
        *(uint2*)&Kp[key * 40 + 4 * dq] = make_uint2(pkbf(fk.x, fk.y), pkbf(fk.z, fk.w));
        int vb = (4 * dq) * 776 + key;
        Vt[vb] = f2bf(fv.x);
        Vt[vb + 776] = f2bf(fv.y);
        Vt[vb + 1552] = f2bf(fv.z);
        Vt[vb + 2328] = f2bf(fv.w);
    }

    short8 qfrag[3];
#pragma unroll
    for (int qt = 0; qt < 3; ++qt) {
        short8 s = { 0, 0, 0, 0, 0, 0, 0, 0 };
        int qx = qt * 16 + c;
        if (qx < 40) {
            const float* qp = Q + (y * 40 + qx) * ldq + h * HD + g * 8;
            float4 f0 = *(const float4*)qp;
            float4 f1 = *(const float4*)(qp + 4);
            s[0] = (short)f2bf(f0.x * SCALE_QK); s[1] = (short)f2bf(f0.y * SCALE_QK);
            s[2] = (short)f2bf(f0.z * SCALE_QK); s[3] = (short)f2bf(f0.w * SCALE_QK);
            s[4] = (short)f2bf(f1.x * SCALE_QK); s[5] = (short)f2bf(f1.y * SCALE_QK);
            s[6] = (short)f2bf(f1.z * SCALE_QK); s[7] = (short)f2bf(f1.w * SCALE_QK);
        }
        qfrag[qt] = s;
    }
    __syncthreads();

    f32x4 sfr[12][3];
    const f32x4 zf = { 0.f, 0.f, 0.f, 0.f };
#pragma unroll
    for (int i = 0; i < 12; ++i) {
        int ky = 4 * w + i / 3;
        int fx = i % 3;
        short8 kf = *(const short8*)&Kp[(ky * 48 + fx * 16 + c) * 40 + 8 * g];
#pragma unroll
        for (int qt = 0; qt < 3; ++qt)
            sfr[i][qt] = __builtin_amdgcn_mfma_f32_16x16x32_bf16(kf, qfrag[qt], zf, 0, 0, 0);
    }

    float mw[3] = { -1e30f, -1e30f, -1e30f };
#pragma unroll
    for (int i = 0; i < 12; ++i) {
        int ky = 4 * w + i / 3, fx = i % 3;
        int yy = y + ky - 7;
        bool rowok = (yy >= 0) && (yy < 40);
        int xxb = fx * 16 + 4 * g;
#pragma unroll
        for (int qt = 0; qt < 3; ++qt) {
            int qx = qt * 16 + c;
#pragma unroll
            for (int r = 0; r < 4; ++r) {
                int xx = xxb + r;
                int dd = xx - qx;
                bool ok = rowok && (xx < 40) && (dd <= 7) && (dd >= -7);
                float v = ok ? sfr[i][qt][r] : -1e9f;
                sfr[i][qt][r] = v;
                mw[qt] = fmaxf(mw[qt], v);
            }
        }
    }
#pragma unroll
    for (int qt = 0; qt < 3; ++qt) {
        mw[qt] = fmaxf(mw[qt], __shfl_xor(mw[qt], 16, 64));
        mw[qt] = fmaxf(mw[qt], __shfl_xor(mw[qt], 32, 64));
    }
    if (lane < 16) {
#pragma unroll
        for (int qt = 0; qt < 3; ++qt) mred[w][qt][lane] = mw[qt];
    }
    __syncthreads();
    float M[3];
#pragma unroll
    for (int qt = 0; qt < 3; ++qt)
        M[qt] = fmaxf(fmaxf(mred[0][qt][c], mred[1][qt][c]),
                      fmaxf(mred[2][qt][c], mred[3][qt][c]));

    float lsum[3] = { 0.f, 0.f, 0.f };
    f32x4 acc_o[2][3] = {};
    int src_lo = 16 * ((2 * g) & 3) + c;
    int src_hi = 16 * ((2 * g + 1) & 3) + c;
    bool hisel = (g >= 2);
#pragma unroll
    for (int chk = 0; chk < 6; ++chk) {
        short8 pfrag[3];
#pragma unroll
        for (int qt = 0; qt < 3; ++qt) {
            float p00 = __expf(sfr[2 * chk][qt][0] - M[qt]);
            float p01 = __expf(sfr[2 * chk][qt][1] - M[qt]);
            float p02 = __expf(sfr[2 * chk][qt][2] - M[qt]);
            float p03 = __expf(sfr[2 * chk][qt][3] - M[qt]);
            float p10 = __expf(sfr[2 * chk + 1][qt][0] - M[qt]);
            float p11 = __expf(sfr[2 * chk + 1][qt][1] - M[qt]);
            float p12 = __expf(sfr[2 * chk + 1][qt][2] - M[qt]);
            float p13 = __expf(sfr[2 * chk + 1][qt][3] - M[qt]);
            lsum[qt] += ((p00 + p01) + (p02 + p03)) + ((p10 + p11) + (p12 + p13));
            unsigned w00 = pkbf(p00, p01), w01 = pkbf(p02, p03);
            unsigned w10 = pkbf(p10, p11), w11 = pkbf(p12, p13);
            unsigned a0 = __shfl(w00, src_lo, 64);
            unsigned a1 = __shfl(w10, src_lo, 64);
            unsigned b0 = __shfl(w01, src_lo, 64);
            unsigned b1 = __shfl(w11, src_lo, 64);
            unsigned c0 = __shfl(w00, src_hi, 64);
            unsigned c1 = __shfl(w10, src_hi, 64);
            unsigned d0 = __shfl(w01, src_hi, 64);
            unsigned d1 = __shfl(w11, src_hi, 64);
            union { short8 s8; unsigned u[4]; } P;
            P.u[0] = hisel ? a1 : a0;
            P.u[1] = hisel ? b1 : b0;
            P.u[2] = hisel ? c1 : c0;
            P.u[3] = hisel ? d1 : d0;
            pfrag[qt] = P.s8;
        }
        int jb = 32 * (6 * w + chk);
        short8 vf0 = *(const short8*)&Vt[c * 776 + jb + 8 * g];
        short8 vf1 = *(const short8*)&Vt[(16 + c) * 776 + jb + 8 * g];
#pragma unroll
        for (int qt = 0; qt < 3; ++qt) {
            acc_o[0][qt] = __builtin_amdgcn_mfma_f32_16x16x32_bf16(vf0, pfrag[qt], acc_o[0][qt], 0, 0, 0);
            acc_o[1][qt] = __builtin_amdgcn_mfma_f32_16x16x32_bf16(vf1, pfrag[qt], acc_o[1][qt], 0, 0, 0);
        }
    }

#pragma unroll
    for (int qt = 0; qt < 3; ++qt) {
        lsum[qt] += __shfl_xor(lsum[qt], 16, 64);
        lsum[qt] += __shfl_xor(lsum[qt], 32, 64);
    }
    if (lane < 16) {
#pragma unroll
        for (int qt = 0; qt < 3; ++qt) lred[w][qt][lane] = lsum[qt];
    }
    if (w > 0) {
#pragma unroll
        for (int dt = 0; dt < 2; ++dt)
#pragma unroll
            for (int qt = 0; qt < 3; ++qt)
                *(f32x4*)&Osh[w - 1][dt][qt][lane][0] = acc_o[dt][qt];
    }
    __syncthreads();
    if (w == 0) {
#pragma unroll
        for (int qt = 0; qt < 3; ++qt) {
            int qx = qt * 16 + c;
            if (qx >= 40) continue;
            float L = (lred[0][qt][c] + lred[1][qt][c]) + (lred[2][qt][c] + lred[3][qt][c]);
            float inv = 1.f / L;
#pragma unroll
            for (int dt = 0; dt < 2; ++dt) {
                f32x4 o1 = *(const f32x4*)&Osh[0][dt][qt][lane][0];
                f32x4 o2 = *(const f32x4*)&Osh[1][dt][qt][lane][0];
                f32x4 o3 = *(const f32x4*)&Osh[2][dt][qt][lane][0];
                float4 r;
                r.x = (acc_o[dt][qt][0] + o1[0] + o2[0] + o3[0]) * inv;
                r.y = (acc_o[dt][qt][1] + o1[1] + o2[1] + o3[1]) * inv;
                r.z = (acc_o[dt][qt][2] + o1[2] + o2[2] + o3[2]) * inv;
                r.w = (acc_o[dt][qt][3] + o1[3] + o2[3] + o3[3]) * inv;
                *(float4*)(O + (y * 40 + qx) * ldo + h * HD + dt * 16 + 4 * g) = r;
            }
        }
    }
}

// merged prep: dw_k transpose + [lt|st] weight concat + bias sum
__global__ __launch_bounds__(256) void prep_misc(const float* __restrict__ Kw,
                                                 const float* __restrict__ lt_wo,
                                                 const float* __restrict__ lt_bo,
                                                 const float* __restrict__ st_wo,
                                                 const float* __restrict__ st_bo,
                                                 float* __restrict__ Kt,
                                                 float* __restrict__ wcat,
                                                 float* __restrict__ bsum) {
    int idx = blockIdx.x * 256 + threadIdx.x;   // 0..65535
    int n = idx >> 8, k = idx & 255;
    wcat[n * 512 + k] = lt_wo[idx];
    wcat[n * 512 + 256 + k] = st_wo[idx];
    if (idx < 256) bsum[idx] = lt_bo[idx] + st_bo[idx];
    if (idx < 25 * DFF_) {
        int kk = idx >> 10, c = idx & 1023;
        Kt[idx] = Kw[c * 25 + kk];
    }
}

// GroupNorm partials: grid (32 groups, 8 chunks); deterministic partial sums.
__global__ __launch_bounds__(256) void gn_partial(const float* __restrict__ X,
                                                  float* __restrict__ gstat) {
    __shared__ float sh4[4];
    int g = blockIdx.x, chunk = blockIdx.y;
    int base = g * 32;
    float s = 0.f, s2 = 0.f;
    for (int i = threadIdx.x; i < 200 * 32; i += 256) {
        int l = chunk * 200 + (i >> 5), c = i & 31;
        float v = X[l * DFF_ + base + c];
        s += v;
        s2 += v * v;
    }
    s = blockReduceSum(s, sh4);
    s2 = blockReduceSum(s2, sh4);
    if (threadIdx.x == 0) {
        gstat[g * 8 + chunk] = s;
        gstat[256 + g * 8 + chunk] = s2;
    }
}

// GroupNorm apply + exact GELU, float4-vectorized.
__global__ __launch_bounds__(256) void gn_apply(const float* __restrict__ X,
                                                const float* __restrict__ gstat,
                                                const float* __restrict__ g,
                                                const float* __restrict__ b,
                                                float* __restrict__ Y) {
    int idx = blockIdx.x * 256 + threadIdx.x;
    int e4 = idx * 4;
    int c = e4 & 1023;
    int grp = c >> 5;
    float s = 0.f, s2 = 0.f;
#pragma unroll
    for (int i = 0; i < 8; ++i) {
        s += gstat[grp * 8 + i];
        s2 += gstat[256 + grp * 8 + i];
    }
    const float invn = 1.0f / 51200.f;
    float mean = s * invn;
    float rs = rsqrtf(s2 * invn - mean * mean + 1e-5f);
    float4 v = *(const float4*)(X + e4);
    float4 gg = *(const float4*)(g + c);
    float4 bb = *(const float4*)(b + c);
    float4 r;
    float y0 = (v.x - mean) * rs * gg.x + bb.x;
    float y1 = (v.y - mean) * rs * gg.y + bb.y;
    float y2 = (v.z - mean) * rs * gg.z + bb.z;
    float y3 = (v.w - mean) * rs * gg.w + bb.w;
    r.x = 0.5f * y0 * (1.0f + erff(y0 * 0.70710678118654752f));
    r.y = 0.5f * y1 * (1.0f + erff(y1 * 0.70710678118654752f));
    r.z = 0.5f * y2 * (1.0f + erff(y2 * 0.70710678118654752f));
    r.w = 0.5f * y3 * (1.0f + erff(y3 * 0.70710678118654752f));
    *(float4*)(Y + e4) = r;
}

// depthwise 5x5 conv v2 (verified)
__global__ __launch_bounds__(256) void dwconv_v2(const float* __restrict__ X,
                                                 const float* __restrict__ Kt,
                                                 float* __restrict__ Y) {
    int l = blockIdx.x;
    int c4 = threadIdx.x * 4;
    int y = l / GRID_W, x = l - y * GRID_W;
    float4 acc = make_float4(0.f, 0.f, 0.f, 0.f);
    if (y >= 2 && y < GRID_H - 2 && x >= 2 && x < GRID_W - 2) {
#pragma unroll
        for (int ky = 0; ky < 5; ++ky) {
#pragma unroll
            for (int kx = 0; kx < 5; ++kx) {
                float4 xv = *(const float4*)(X + ((y + ky - 2) * GRID_W + x + kx - 2) * DFF_ + c4);
                float4 wv = *(const float4*)(Kt + (ky * 5 + kx) * DFF_ + c4);
                acc.x += xv.x * wv.x; acc.y += xv.y * wv.y;
                acc.z += xv.z * wv.z; acc.w += xv.w * wv.w;
            }
        }
    } else {
#pragma unroll
        for (int ky = 0; ky < 5; ++ky) {
            int yy = y + ky - 2;
            if (yy < 0 || yy >= GRID_H) continue;
#pragma unroll
            for (int kx = 0; kx < 5; ++kx) {
                int xx = x + kx - 2;
                if (xx < 0 || xx >= GRID_W) continue;
                float4 xv = *(const float4*)(X + (yy * GRID_W + xx) * DFF_ + c4);
                float4 wv = *(const float4*)(Kt + (ky * 5 + kx) * DFF_ + c4);
                acc.x += xv.x * wv.x; acc.y += xv.y * wv.y;
                acc.z += xv.z * wv.z; acc.w += xv.w * wv.w;
            }
        }
    }
    *(float4*)(Y + l * DFF_ + c4) = acc;
}

extern "C" void kernel_launch(void* const* d_in, const int* in_sizes, int n_in,
                              void* d_out, int out_size, void* d_ws, size_t ws_size,
                              hipStream_t stream) {
    (void)in_sizes; (void)n_in; (void)out_size; (void)ws_size;
    const float* tgt = (const float*)d_in[0];
    const float* curr_id_emb = (const float*)d_in[1];
    const float* self_pos = (const float*)d_in[2];
    const float* ln1_g = (const float*)d_in[3];
    const float* ln1_b = (const float*)d_in[4];
    const float* sa_wq = (const float*)d_in[5];
    const float* sa_bq = (const float*)d_in[6];
    const float* sa_wk = (const float*)d_in[7];
    const float* sa_bk = (const float*)d_in[8];
    const float* sa_wv = (const float*)d_in[9];
    const float* sa_bv = (const float*)d_in[10];
    const float* sa_wo = (const float*)d_in[11];
    const float* sa_bo = (const float*)d_in[12];
    const float* ln2_g = (const float*)d_in[13];
    const float* ln2_b = (const float*)d_in[14];
    const float* w_qv = (const float*)d_in[15];
    const float* b_qv = (const float*)d_in[16];
    const float* w_id = (const float*)d_in[17];
    const float* b_id = (const float*)d_in[18];
    const float* lt_wo = (const float*)d_in[19];
    const float* lt_bo = (const float*)d_in[20];
    const float* st_wo = (const float*)d_in[21];
    const float* st_bo = (const float*)d_in[22];
    const float* ln3_g = (const float*)d_in[23];
    const float* ln3_b = (const float*)d_in[24];
    const float* w1 = (const float*)d_in[25];
    const float* b1 = (const float*)d_in[26];
    const float* gn_g = (const float*)d_in[27];
    const float* gn_b = (const float*)d_in[28];
    const float* dw_k = (const float*)d_in[29];
    const float* w2 = (const float*)d_in[30];
    const float* b2 = (const float*)d_in[31];
    float* out = (float*)d_out;

    float* ws = (float*)d_ws;
    const int LC = L_SEQ * CDIM;           // 409600
    float* bufA = ws;                      // ln outputs
    float* bufB = bufA + LC;               // qk_in / tgt_b
    float* bufC = bufB + LC;               // q_
    float* bufD = bufC + LC;               // k_
    float* bufE = bufD + LC;               // v_
    float* bufG = bufE + LC;               // tgt1
    float* bufFW = bufG + LC;              // attn outs (1600x512)
    float* bufH = bufFW + L_SEQ * 512;     // qv (1600x512); later gstat
    float* bufI = bufH + L_SEQ * 512;      // idkv (1600x264)
    float* bufX = bufI + L_SEQ * 264;      // w1 out (1600x1024)
    float* bufY = bufX + L_SEQ * DFF_;     // gn+gelu out
    float* bufZ = bufY + L_SEQ * DFF_;     // conv out
    float* bufW = bufZ + L_SEQ * DFF_;     // transposed dw_k (25x1024)
    float* wcat = bufW + 25 * DFF_;        // concat lt/st weights (256x512)
    float* bsum = wcat + 256 * 512;        // summed biases (256)
    unsigned short* Kf = (unsigned short*)(bsum + 256);   // NH*13*4096 shorts
    unsigned short* Vf = Kf + NH * NTILE * 4096;          // NH*13*6144 shorts

    dim3 blk(256);
    dim3 mhaGrid(L_SEQ / QBLK, NH);        // (50, 8)
    dim3 prepGrid(NTILE, NH);              // (13, 8)
    auto J = [](const float* A, const float* W, const float* bias, const float* res,
                float* C, int N, int K) {
        GJob j; j.A = A; j.W = W; j.bias = bias; j.res = res; j.C = C; j.N = N; j.K = K;
        return j;
    };

    // 0. merged prep (independent)
    prep_misc<<<256, blk, 0, stream>>>(dw_k, lt_wo, lt_bo, st_wo, st_bo, bufW, wcat, bsum);
    // 1. LN1: bufA = ln(tgt), bufB = bufA + self_pos
    ln_kernel<<<L_SEQ, blk, 0, stream>>>(tgt, ln1_g, ln1_b, self_pos, bufA, bufB);
    // 2. q,k,v projections (one batched dispatch, 300 blocks)
    {
        GJob jq = J(bufB, sa_wq, sa_bq, nullptr, bufC, CDIM, CDIM);
        GJob jk = J(bufB, sa_wk, sa_bk, nullptr, bufD, CDIM, CDIM);
        GJob jv = J(bufA, sa_wv, sa_bv, nullptr, bufE, CDIM, CDIM);
        gemm_mfma<<<dim3(4, 25, 3), blk, 0, stream>>>(jq, jk, jv);
    }
    // 2b. build K/V fragment tiles for self-attn
    prep_kv<<<prepGrid, blk, 0, stream>>>(bufD, CDIM, bufE, CDIM, nullptr, Kf, Vf);
    // 3. self attention -> bufFW (ldo=256)
    mha_mfma<<<mhaGrid, blk, 0, stream>>>(bufC, CDIM, Kf, Vf, bufFW, CDIM);
    // 4. out proj + residual -> tgt1 (bufG)
    {
        GJob jo = J(bufFW, sa_wo, sa_bo, tgt, bufG, CDIM, CDIM);
        gemm_mfma<<<dim3(4, 25, 1), blk, 0, stream>>>(jo, jo, jo);
    }
    // 5. LN2 -> bufA
    ln_kernel<<<L_SEQ, blk, 0, stream>>>(bufG, ln2_g, ln2_b, nullptr, bufA, nullptr);
    // 6. qv + idkv (one batched dispatch)
    {
        GJob jqv = J(bufA, w_qv, b_qv, nullptr, bufH, 512, CDIM);
        GJob jid = J(curr_id_emb, w_id, b_id, nullptr, bufI, 264, CDIM);
        gemm_mfma<<<dim3(8, 25, 2), blk, 0, stream>>>(jqv, jid, jid);
    }
    // 6b. build gated K/V fragment tiles for long-term attn
    prep_kv<<<prepGrid, blk, 0, stream>>>(bufH, 512, bufH + 256, 512, bufI, Kf, Vf);
    // 7. long-term attention -> bufFW cols 0..255
    mha_mfma<<<mhaGrid, blk, 0, stream>>>(bufH, 512, Kf, Vf, bufFW, 512);
    // 8. local attention (gating fused) -> bufFW cols 256..511
    local_mfma<<<dim3(GRID_H, NH), blk, 0, stream>>>(bufH, 512, bufH, 512, bufH + 256, 512, bufI, bufFW + 256, 512);
    // 9. merged lt/st projection: tgt_b = tgt1 + [mha2|local] @ wcat^T + bsum -> bufB
    {
        GJob jm = J(bufFW, wcat, bsum, bufG, bufB, CDIM, 512);
        gemm_mfma<<<dim3(4, 25, 1), blk, 0, stream>>>(jm, jm, jm);
    }
    // 10. LN3 -> bufA
    ln_kernel<<<L_SEQ, blk, 0, stream>>>(bufB, ln3_g, ln3_b, nullptr, bufA, nullptr);
    // 11. x = bufA @ w1^T -> bufX
    {
        GJob jw1 = J(bufA, w1, b1, nullptr, bufX, DFF_, CDIM);
        gemm_mfma<<<dim3(16, 25, 1), blk, 0, stream>>>(jw1, jw1, jw1);
    }
    // 12. GroupNorm + GELU -> bufY (bufH dead; reuse as gstat)
    gn_partial<<<dim3(32, 8), blk, 0, stream>>>(bufX, bufH);
    gn_apply<<<L_SEQ, blk, 0, stream>>>(bufX, bufH, gn_g, gn_b, bufY);
    // 13. depthwise conv -> bufZ
    dwconv_v2<<<L_SEQ, blk, 0, stream>>>(bufY, bufW, bufZ);
    // 14. final proj + residual(tgt_b) -> out
    {
        GJob jw2 = J(bufZ, w2, b2, bufB, out, CDIM, DFF_);
        gemm_mfma<<<dim3(4, 25, 1), blk, 0, stream>>>(jw2, jw2, jw2);
    }
}

// Round 13
// 339.015 us; speedup vs baseline: 1.1439x; 1.0468x over previous
//
#include <hip/hip_runtime.h>
#include <math.h>

#define L_SEQ 1600
#define CDIM 256
#define NH 8
#define HD 32
#define GRID_H 40
#define GRID_W 40
#define DFF_ 1024
#define SCALE_QK 0.17677669529663687f
#define NTILE 13   // ceil(1600/128)

typedef __attribute__((ext_vector_type(8))) short short8;
typedef __attribute__((ext_vector_type(4))) float f32x4;

__device__ __forceinline__ float waveReduceSum(float v) {
#pragma unroll
    for (int off = 32; off > 0; off >>= 1) v += __shfl_down(v, off, 64);
    return v;
}
__device__ __forceinline__ float blockReduceSum(float v, float* sh4) {
    v = waveReduceSum(v);
    int lane = threadIdx.x & 63, wid = threadIdx.x >> 6;
    __syncthreads();
    if (lane == 0) sh4[wid] = v;
    __syncthreads();
    return sh4[0] + sh4[1] + sh4[2] + sh4[3];
}

__device__ __forceinline__ unsigned short f2bf(float x) {
    union { float f; unsigned u; } v; v.f = x;
    unsigned r = (v.u + 0x7FFFu + ((v.u >> 16) & 1u)) >> 16;
    return (unsigned short)r;
}
__device__ __forceinline__ unsigned pkbf(float lo, float hi) {
    return (unsigned)f2bf(lo) | ((unsigned)f2bf(hi) << 16);
}

// LayerNorm over C=256; one block per row. out2 = out + addin (optional)
__global__ __launch_bounds__(256) void ln_kernel(const float* __restrict__ x,
                                                 const float* __restrict__ g,
                                                 const float* __restrict__ b,
                                                 const float* __restrict__ addin,
                                                 float* __restrict__ out,
                                                 float* __restrict__ out2) {
    __shared__ float sh4[4];
    int row = blockIdx.x;
    int c = threadIdx.x;
    float v = x[row * CDIM + c];
    float mean = blockReduceSum(v, sh4) * (1.0f / CDIM);
    float d = v - mean;
    float var = blockReduceSum(d * d, sh4) * (1.0f / CDIM);
    float y = d * rsqrtf(var + 1e-5f) * g[c] + b[c];
    out[row * CDIM + c] = y;
    if (out2) out2[row * CDIM + c] = y + addin[row * CDIM + c];
}

// ---------------------------------------------------------------------------
// bf16 MFMA GEMM, batched up to 3 jobs via blockIdx.z (verified body).
// ---------------------------------------------------------------------------
struct GJob {
    const float* A; const float* W; const float* bias; const float* res;
    float* C; int N; int K;
};

__global__ __launch_bounds__(256) void gemm_mfma(GJob j0, GJob j1, GJob j2) {
    GJob j = j0;
    if (blockIdx.z == 1) j = j1;
    else if (blockIdx.z == 2) j = j2;
    const float* __restrict__ A = j.A;
    const float* __restrict__ W = j.W;
    const float* bias = j.bias;
    const float* res = j.res;
    float* __restrict__ C = j.C;
    int N = j.N, K = j.K;

    __shared__ unsigned short Al[2][4][64][8];
    __shared__ unsigned short Bl[2][4][64][8];
    int tid = threadIdx.x;
    int bm = blockIdx.y * 64, bn = blockIdx.x * 64;
    if (bn >= N) return;
    int lane = tid & 63, wave = tid >> 6;
    int wr = wave >> 1, wc = wave & 1;

    int srow = tid >> 3;
    int q = tid & 7;
    int e0 = (q & 1) * 4;

    f32x4 acc[2][2] = {};
    int nsteps = K >> 5;

    float4 ra[2], rb[2];
    {
#pragma unroll
        for (int r = 0; r < 2; ++r) {
            int row = srow + 32 * r;
            ra[r] = *(const float4*)(A + (bm + row) * K + 4 * q);
            int n = bn + row;
            rb[r] = (n < N) ? *(const float4*)(W + n * K + 4 * q)
                            : make_float4(0.f, 0.f, 0.f, 0.f);
        }
#pragma unroll
        for (int r = 0; r < 2; ++r) {
            int row = srow + 32 * r;
            int frag = (row >> 4), l = (row & 15) + 16 * (q >> 1);
            *(uint2*)&Al[0][frag][l][e0] = make_uint2(pkbf(ra[r].x, ra[r].y), pkbf(ra[r].z, ra[r].w));
            *(uint2*)&Bl[0][frag][l][e0] = make_uint2(pkbf(rb[r].x, rb[r].y), pkbf(rb[r].z, rb[r].w));
        }
    }
    __syncthreads();

    for (int s = 0; s < nsteps; ++s) {
        bool more = (s + 1) < nsteps;
        if (more) {
            int k0 = (s + 1) << 5;
#pragma unroll
            for (int r = 0; r < 2; ++r) {
                int row = srow + 32 * r;
                ra[r] = *(const float4*)(A + (bm + row) * K + k0 + 4 * q);
                int n = bn + row;
                rb[r] = (n < N) ? *(const float4*)(W + n * K + k0 + 4 * q)
                                : make_float4(0.f, 0.f, 0.f, 0.f);
            }
        }
        {
            int buf = s & 1;
            short8 af[2], bfr[2];
#pragma unroll
            for (int i = 0; i < 2; ++i) {
                af[i] = *(const short8*)&Al[buf][2 * wr + i][lane][0];
                bfr[i] = *(const short8*)&Bl[buf][2 * wc + i][lane][0];
            }
#pragma unroll
            for (int i = 0; i < 2; ++i)
#pragma unroll
                for (int jj = 0; jj < 2; ++jj)
                    acc[i][jj] = __builtin_amdgcn_mfma_f32_16x16x32_bf16(af[i], bfr[jj], acc[i][jj], 0, 0, 0);
        }
        if (more) {
            int buf = (s + 1) & 1;
#pragma unroll
            for (int r = 0; r < 2; ++r) {
                int row = srow + 32 * r;
                int frag = (row >> 4), l = (row & 15) + 16 * (q >> 1);
                *(uint2*)&Al[buf][frag][l][e0] = make_uint2(pkbf(ra[r].x, ra[r].y), pkbf(ra[r].z, ra[r].w));
                *(uint2*)&Bl[buf][frag][l][e0] = make_uint2(pkbf(rb[r].x, rb[r].y), pkbf(rb[r].z, rb[r].w));
            }
        }
        __syncthreads();
    }

#pragma unroll
    for (int jj = 0; jj < 2; ++jj) {
        int col = bn + wc * 32 + jj * 16 + (lane & 15);
        if (col >= N) continue;
        float bv = bias ? bias[col] : 0.f;
#pragma unroll
        for (int i = 0; i < 2; ++i) {
            int rbase = bm + wr * 32 + i * 16 + ((lane >> 4) << 2);
#pragma unroll
            for (int r = 0; r < 4; ++r) {
                int row = rbase + r;
                float v = acc[i][jj][r] + bv;
                if (res) v += res[row * N + col];
                C[row * N + col] = v;
            }
        }
    }
}

// ---------------------------------------------------------------------------
// prep_kv: build bf16 fragment-layout K/V tiles per (head, 128-key tile),
// with optional id-gating; optionally also writes gated K/V as plain
// row-major f32 (stride CDIM) for the local-attention kernel.
// ---------------------------------------------------------------------------
#define KTJ 128
__global__ __launch_bounds__(256) void prep_kv(const float* __restrict__ K, int ldk,
                                               const float* __restrict__ V, int ldv,
                                               const float* __restrict__ idkv,
                                               unsigned short* __restrict__ Kf,
                                               unsigned short* __restrict__ Vf,
                                               float* __restrict__ gK,
                                               float* __restrict__ gV) {
    int tile = blockIdx.x, h = blockIdx.y;
    int t = tile * KTJ;
    int tid = threadIdx.x;
    unsigned short* kb = Kf + (h * NTILE + tile) * 4096;
    unsigned short* vb = Vf + (h * NTILE + tile) * 6144;
    // ---- K fragment (gated) ----
    {
        int jrow = tid >> 1;
        int dhalf = (tid & 1) * 16;
        int jj = t + jrow;
        float4 f0, f1, f2, f3;
        if (jj < L_SEQ) {
            const float4* kp = (const float4*)(K + jj * ldk + h * HD + dhalf);
            f0 = kp[0]; f1 = kp[1]; f2 = kp[2]; f3 = kp[3];
            if (idkv) {
                float gt = 1.f + tanhf(idkv[jj * 264 + h]);
                f0.x *= gt; f0.y *= gt; f0.z *= gt; f0.w *= gt;
                f1.x *= gt; f1.y *= gt; f1.z *= gt; f1.w *= gt;
                f2.x *= gt; f2.y *= gt; f2.z *= gt; f2.w *= gt;
                f3.x *= gt; f3.y *= gt; f3.z *= gt; f3.w *= gt;
            }
            if (gK) {
                float4* gp = (float4*)(gK + jj * CDIM + h * HD + dhalf);
                gp[0] = f0; gp[1] = f1; gp[2] = f2; gp[3] = f3;
            }
        } else {
            f0 = f1 = f2 = f3 = make_float4(0.f, 0.f, 0.f, 0.f);
        }
        int jt = jrow >> 4;
        int laneA = (jrow & 15) + dhalf * 2;
        short8 s0, s1;
        s0[0]=f2bf(f0.x); s0[1]=f2bf(f0.y); s0[2]=f2bf(f0.z); s0[3]=f2bf(f0.w);
        s0[4]=f2bf(f1.x); s0[5]=f2bf(f1.y); s0[6]=f2bf(f1.z); s0[7]=f2bf(f1.w);
        s1[0]=f2bf(f2.x); s1[1]=f2bf(f2.y); s1[2]=f2bf(f2.z); s1[3]=f2bf(f2.w);
        s1[4]=f2bf(f3.x); s1[5]=f2bf(f3.y); s1[6]=f2bf(f3.z); s1[7]=f2bf(f3.w);
        *(short8*)&kb[(jt * 64 + laneA) * 8] = s0;
        *(short8*)&kb[(jt * 64 + laneA + 16) * 8] = s1;
    }
    // ---- V fragment (transposed, +id_v) ----
    {
        int vjq = tid >> 3, vdq = tid & 7;
        int vjr = 4 * vjq, vd0 = 4 * vdq;
        int vjc = vjr >> 5, vdt = vd0 >> 4, vjg = (vjr & 31) >> 3, ve0 = vjr & 7;
        float4 rr[4];
        int j0 = t + vjr;
#pragma unroll
        for (int r = 0; r < 4; ++r) {
            int jj = j0 + r;
            if (jj < L_SEQ) {
                float4 fv = *(const float4*)(V + jj * ldv + h * HD + vd0);
                if (idkv) {
                    float4 av = *(const float4*)(idkv + jj * 264 + 8 + h * HD + vd0);
                    fv.x += av.x; fv.y += av.y; fv.z += av.z; fv.w += av.w;
                }
                rr[r] = fv;
                if (gV) *(float4*)(gV + jj * CDIM + h * HD + vd0) = fv;
            } else {
                rr[r] = make_float4(0.f, 0.f, 0.f, 0.f);
            }
        }
        float col[4][4] = {
            { rr[0].x, rr[1].x, rr[2].x, rr[3].x },
            { rr[0].y, rr[1].y, rr[2].y, rr[3].y },
            { rr[0].z, rr[1].z, rr[2].z, rr[3].z },
            { rr[0].w, rr[1].w, rr[2].w, rr[3].w } };
#pragma unroll
        for (int dd = 0; dd < 4; ++dd) {
            int laneV = ((vd0 + dd) & 15) + 16 * vjg;
            uint2 pk;
            pk.x = pkbf(col[dd][0], col[dd][1]);
            pk.y = pkbf(col[dd][2], col[dd][3]);
            *(uint2*)&vb[((vjc * 2 + vdt) * 64 + laneV) * 12 + ve0] = pk;
        }
    }
}

// ---------------------------------------------------------------------------
// MFMA flash attention, QBLK=32; K/V read from prebuilt fragment buffers.
// ---------------------------------------------------------------------------
#define QBLK 32
__global__ __launch_bounds__(256) void mha_mfma(const float* __restrict__ Q, int ldq,
                                                const unsigned short* __restrict__ Kf,
                                                const unsigned short* __restrict__ Vf,
                                                float* __restrict__ O, int ldo) {
    __shared__ unsigned short Kl[8][64][8];
    __shared__ unsigned short Vl[4][2][64][12];
    __shared__ float mred[4][2][16];
    __shared__ float lred[4][2][16];
    __shared__ float Osh[3][2][2][64][4];
    int h = blockIdx.y;
    int qbase = blockIdx.x * QBLK;
    int tid = threadIdx.x;
    int w = tid >> 6, lane = tid & 63;
    int g = lane >> 4, c = lane & 15;

    short8 qfrag[2];
#pragma unroll
    for (int qt = 0; qt < 2; ++qt) {
        const float* qp = Q + (qbase + qt * 16 + c) * ldq + h * HD + g * 8;
        float4 f0 = *(const float4*)qp;
        float4 f1 = *(const float4*)(qp + 4);
        short8 s;
        s[0] = (short)f2bf(f0.x * SCALE_QK); s[1] = (short)f2bf(f0.y * SCALE_QK);
        s[2] = (short)f2bf(f0.z * SCALE_QK); s[3] = (short)f2bf(f0.w * SCALE_QK);
        s[4] = (short)f2bf(f1.x * SCALE_QK); s[5] = (short)f2bf(f1.y * SCALE_QK);
        s[6] = (short)f2bf(f1.z * SCALE_QK); s[7] = (short)f2bf(f1.w * SCALE_QK);
        qfrag[qt] = s;
    }

    float m[2] = { -INFINITY, -INFINITY };
    float l[2] = { 0.f, 0.f };
    f32x4 acc_o[2][2] = {};

    int src_lo = 16 * ((2 * g) & 3) + c;
    int src_hi = 16 * ((2 * g + 1) & 3) + c;
    bool hisel = (g >= 2);

    const float4* kfb = (const float4*)(Kf + h * NTILE * 4096);
    const float4* vfb = (const float4*)(Vf + h * NTILE * 6144);
    float4* kdst = (float4*)&Kl[0][0][0];
    float4* vdst = (float4*)&Vl[0][0][0][0];

    for (int tile = 0; tile < NTILE; ++tile) {
        int t = tile * KTJ;
        {
            const float4* ks = kfb + tile * 512;
            const float4* vs = vfb + tile * 768;
            kdst[tid] = ks[tid];
            kdst[tid + 256] = ks[tid + 256];
            vdst[tid] = vs[tid];
            vdst[tid + 256] = vs[tid + 256];
            vdst[tid + 512] = vs[tid + 512];
        }
        __syncthreads();

        bool alive = (t + 32 * w) < L_SEQ;
        if (alive) {
            short8 kf0 = *(const short8*)&Kl[2 * w][lane][0];
            short8 kf1 = *(const short8*)&Kl[2 * w + 1][lane][0];
            f32x4 zero = { 0.f, 0.f, 0.f, 0.f };
            f32x4 s[2][2];
            s[0][0] = __builtin_amdgcn_mfma_f32_16x16x32_bf16(kf0, qfrag[0], zero, 0, 0, 0);
            s[0][1] = __builtin_amdgcn_mfma_f32_16x16x32_bf16(kf0, qfrag[1], zero, 0, 0, 0);
            s[1][0] = __builtin_amdgcn_mfma_f32_16x16x32_bf16(kf1, qfrag[0], zero, 0, 0, 0);
            s[1][1] = __builtin_amdgcn_mfma_f32_16x16x32_bf16(kf1, qfrag[1], zero, 0, 0, 0);

            short8 pfrag[2];
#pragma unroll
            for (int qt = 0; qt < 2; ++qt) {
                float mx = s[0][qt][0];
                mx = fmaxf(mx, s[0][qt][1]); mx = fmaxf(mx, s[0][qt][2]); mx = fmaxf(mx, s[0][qt][3]);
                mx = fmaxf(mx, s[1][qt][0]); mx = fmaxf(mx, s[1][qt][1]);
                mx = fmaxf(mx, s[1][qt][2]); mx = fmaxf(mx, s[1][qt][3]);
                mx = fmaxf(mx, __shfl_xor(mx, 16, 64));
                mx = fmaxf(mx, __shfl_xor(mx, 32, 64));
                float nm = fmaxf(m[qt], mx);
                float alpha = __expf(m[qt] - nm);
                m[qt] = nm;
                float p00 = __expf(s[0][qt][0] - nm), p01 = __expf(s[0][qt][1] - nm);
                float p02 = __expf(s[0][qt][2] - nm), p03 = __expf(s[0][qt][3] - nm);
                float p10 = __expf(s[1][qt][0] - nm), p11 = __expf(s[1][qt][1] - nm);
                float p12 = __expf(s[1][qt][2] - nm), p13 = __expf(s[1][qt][3] - nm);
                float ts = ((p00 + p01) + (p02 + p03)) + ((p10 + p11) + (p12 + p13));
                ts += __shfl_xor(ts, 16, 64);
                ts += __shfl_xor(ts, 32, 64);
                l[qt] = l[qt] * alpha + ts;
#pragma unroll
                for (int dt = 0; dt < 2; ++dt) {
                    acc_o[dt][qt][0] *= alpha; acc_o[dt][qt][1] *= alpha;
                    acc_o[dt][qt][2] *= alpha; acc_o[dt][qt][3] *= alpha;
                }
                unsigned w00 = pkbf(p00, p01), w01 = pkbf(p02, p03);
                unsigned w10 = pkbf(p10, p11), w11 = pkbf(p12, p13);
                unsigned a0 = __shfl(w00, src_lo, 64);
                unsigned a1 = __shfl(w10, src_lo, 64);
                unsigned b0 = __shfl(w01, src_lo, 64);
                unsigned b1 = __shfl(w11, src_lo, 64);
                unsigned c0 = __shfl(w00, src_hi, 64);
                unsigned c1 = __shfl(w10, src_hi, 64);
                unsigned d0 = __shfl(w01, src_hi, 64);
                unsigned d1 = __shfl(w11, src_hi, 64);
                union { short8 s8; unsigned u[4]; } P;
                P.u[0] = hisel ? a1 : a0;
                P.u[1] = hisel ? b1 : b0;
                P.u[2] = hisel ? c1 : c0;
                P.u[3] = hisel ? d1 : d0;
                pfrag[qt] = P.s8;
            }

            union { short8 s8; uint2 v[2]; } vf0u, vf1u;
            vf0u.v[0] = *(const uint2*)&Vl[w][0][lane][0];
            vf0u.v[1] = *(const uint2*)&Vl[w][0][lane][4];
            vf1u.v[0] = *(const uint2*)&Vl[w][1][lane][0];
            vf1u.v[1] = *(const uint2*)&Vl[w][1][lane][4];
            acc_o[0][0] = __builtin_amdgcn_mfma_f32_16x16x32_bf16(vf0u.s8, pfrag[0], acc_o[0][0], 0, 0, 0);
            acc_o[0][1] = __builtin_amdgcn_mfma_f32_16x16x32_bf16(vf0u.s8, pfrag[1], acc_o[0][1], 0, 0, 0);
            acc_o[1][0] = __builtin_amdgcn_mfma_f32_16x16x32_bf16(vf1u.s8, pfrag[0], acc_o[1][0], 0, 0, 0);
            acc_o[1][1] = __builtin_amdgcn_mfma_f32_16x16x32_bf16(vf1u.s8, pfrag[1], acc_o[1][1], 0, 0, 0);
        }
        __syncthreads();
    }

    if (g == 0) {
#pragma unroll
        for (int qt = 0; qt < 2; ++qt) { mred[w][qt][c] = m[qt]; lred[w][qt][c] = l[qt]; }
    }
    if (w > 0) {
#pragma unroll
        for (int dt = 0; dt < 2; ++dt)
#pragma unroll
            for (int qt = 0; qt < 2; ++qt)
                *(f32x4*)&Osh[w - 1][dt][qt][lane][0] = acc_o[dt][qt];
    }
    __syncthreads();
    if (w == 0) {
#pragma unroll
        for (int qt = 0; qt < 2; ++qt) {
            float m0_ = mred[0][qt][c], m1_ = mred[1][qt][c];
            float m2_ = mred[2][qt][c], m3_ = mred[3][qt][c];
            float M = fmaxf(fmaxf(m0_, m1_), fmaxf(m2_, m3_));
            float a0 = __expf(m0_ - M), a1 = __expf(m1_ - M);
            float a2 = __expf(m2_ - M), a3 = __expf(m3_ - M);
            float L = a0 * lred[0][qt][c] + a1 * lred[1][qt][c]
                    + a2 * lred[2][qt][c] + a3 * lred[3][qt][c];
            float inv = 1.f / L;
#pragma unroll
            for (int dt = 0; dt < 2; ++dt) {
                f32x4 o1 = *(const f32x4*)&Osh[0][dt][qt][lane][0];
                f32x4 o2 = *(const f32x4*)&Osh[1][dt][qt][lane][0];
                f32x4 o3 = *(const f32x4*)&Osh[2][dt][qt][lane][0];
                float4 r;
                r.x = (acc_o[dt][qt][0] * a0 + o1[0] * a1 + o2[0] * a2 + o3[0] * a3) * inv;
                r.y = (acc_o[dt][qt][1] * a0 + o1[1] * a1 + o2[1] * a2 + o3[1] * a3) * inv;
                r.z = (acc_o[dt][qt][2] * a0 + o1[2] * a1 + o2[2] * a2 + o3[2] * a3) * inv;
                r.w = (acc_o[dt][qt][3] * a0 + o1[3] * a1 + o2[3] * a2 + o3[3] * a3) * inv;
                *(float4*)(O + (qbase + qt * 16 + c) * ldo + h * HD + dt * 16 + 4 * g) = r;
            }
        }
    }
}

// ---------------------------------------------------------------------------
// MFMA local windowed attention (verified; strides + optional id-gating)
// ---------------------------------------------------------------------------
__global__ __launch_bounds__(256, 1) void local_mfma(const float* __restrict__ Q, int ldq,
                                                     const float* __restrict__ K, int ldk,
                                                     const float* __restrict__ V, int ldv,
                                                     const float* __restrict__ idkv,
                                                     float* __restrict__ O, int ldo) {
    __shared__ unsigned short Kp[768 * 40];
    __shared__ unsigned short Vt[32 * 776];
    __shared__ float mred[4][3][16];
    __shared__ float lred[4][3][16];
    __shared__ float Osh[3][2][3][64][4];
    int y = blockIdx.x, h = blockIdx.y;
    int tid = threadIdx.x;
    int w = tid >> 6, lane = tid & 63;
    int g = lane >> 4, c = lane & 15;

#pragma unroll 4
    for (int rep = 0; rep < 24; ++rep) {
        int idx = rep * 256 + tid;
        int key = idx >> 3, dq = idx & 7;
        int ky = key / 48;
        int xx = key - 48 * ky;
        int yy = y + ky - 7;
        bool ok = (xx < 40) && (yy >= 0) && (yy < 40);
        float4 fk = make_float4(0.f, 0.f, 0.f, 0.f);
        float4 fv = make_float4(0.f, 0.f, 0.f, 0.f);
        if (ok) {
            int row = yy * 40 + xx;
            fk = *(const float4*)(K + row * ldk + h * HD + 4 * dq);
            fv = *(const float4*)(V + row * ldv + h * HD + 4 * dq);
            if (idkv) {
                float gt = 1.f + tanhf(idkv[row * 264 + h]);
                fk.x *= gt; fk.y *= gt; fk.z *= gt; fk.w *= gt;
                float4 av = *(const float4*)(idkv + row * 264 + 8 + h * HD + 4 * dq);
                fv.x += av.x; fv.y += av.y; fv.z += av.z; fv.w += av.w;
            }
        }
        *(uint2*)&Kp[key * 40 + 4 * dq] = make_uint2(pkbf(fk.x, fk.y), pkbf(fk.z, fk.w));
        int vb = (4 * dq) * 776 + key;
        Vt[vb] = f2bf(fv.x);
        Vt[vb + 776] = f2bf(fv.y);
        Vt[vb + 1552] = f2bf(fv.z);
        Vt[vb + 2328] = f2bf(fv.w);
    }

    short8 qfrag[3];
#pragma unroll
    for (int qt = 0; qt < 3; ++qt) {
        short8 s = { 0, 0, 0, 0, 0, 0, 0, 0 };
        int qx = qt * 16 + c;
        if (qx < 40) {
            const float* qp = Q + (y * 40 + qx) * ldq + h * HD + g * 8;
            float4 f0 = *(const float4*)qp;
            float4 f1 = *(const float4*)(qp + 4);
            s[0] = (short)f2bf(f0.x * SCALE_QK); s[1] = (short)f2bf(f0.y * SCALE_QK);
            s[2] = (short)f2bf(f0.z * SCALE_QK); s[3] = (short)f2bf(f0.w * SCALE_QK);
            s[4] = (short)f2bf(f1.x * SCALE_QK); s[5] = (short)f2bf(f1.y * SCALE_QK);
            s[6] = (short)f2bf(f1.z * SCALE_QK); s[7] = (short)f2bf(f1.w * SCALE_QK);
        }
        qfrag[qt] = s;
    }
    __syncthreads();

    f32x4 sfr[12][3];
    const f32x4 zf = { 0.f, 0.f, 0.f, 0.f };
#pragma unroll
    for (int i = 0; i < 12; ++i) {
        int ky = 4 * w + i / 3;
        int fx = i % 3;
        short8 kf = *(const short8*)&Kp[(ky * 48 + fx * 16 + c) * 40 + 8 * g];
#pragma unroll
        for (int qt = 0; qt < 3; ++qt)
            sfr[i][qt] = __builtin_amdgcn_mfma_f32_16x16x32_bf16(kf, qfrag[qt], zf, 0, 0, 0);
    }

    float mw[3] = { -1e30f, -1e30f, -1e30f };
#pragma unroll
    for (int i = 0; i < 12; ++i) {
        int ky = 4 * w + i / 3, fx = i % 3;
        int yy = y + ky - 7;
        bool rowok = (yy >= 0) && (yy < 40);
        int xxb = fx * 16 + 4 * g;
#pragma unroll
        for (int qt = 0; qt < 3; ++qt) {
            int qx = qt * 16 + c;
#pragma unroll
            for (int r = 0; r < 4; ++r) {
                int xx = xxb + r;
                int dd = xx - qx;
                bool ok = rowok && (xx < 40) && (dd <= 7) && (dd >= -7);
                float v = ok ? sfr[i][qt][r] : -1e9f;
                sfr[i][qt][r] = v;
                mw[qt] = fmaxf(mw[qt], v);
            }
        }
    }
#pragma unroll
    for (int qt = 0; qt < 3; ++qt) {
        mw[qt] = fmaxf(mw[qt], __shfl_xor(mw[qt], 16, 64));
        mw[qt] = fmaxf(mw[qt], __shfl_xor(mw[qt], 32, 64));
    }
    if (lane < 16) {
#pragma unroll
        for (int qt = 0; qt < 3; ++qt) mred[w][qt][lane] = mw[qt];
    }
    __syncthreads();
    float M[3];
#pragma unroll
    for (int qt = 0; qt < 3; ++qt)
        M[qt] = fmaxf(fmaxf(mred[0][qt][c], mred[1][qt][c]),
                      fmaxf(mred[2][qt][c], mred[3][qt][c]));

    float lsum[3] = { 0.f, 0.f, 0.f };
    f32x4 acc_o[2][3] = {};
    int src_lo = 16 * ((2 * g) & 3) + c;
    int src_hi = 16 * ((2 * g + 1) & 3) + c;
    bool hisel = (g >= 2);
#pragma unroll
    for (int chk = 0; chk < 6; ++chk) {
        short8 pfrag[3];
#pragma unroll
        for (int qt = 0; qt < 3; ++qt) {
            float p00 = __expf(sfr[2 * chk][qt][0] - M[qt]);
            float p01 = __expf(sfr[2 * chk][qt][1] - M[qt]);
            float p02 = __expf(sfr[2 * chk][qt][2] - M[qt]);
            float p03 = __expf(sfr[2 * chk][qt][3] - M[qt]);
            float p10 = __expf(sfr[2 * chk + 1][qt][0] - M[qt]);
            float p11 = __expf(sfr[2 * chk + 1][qt][1] - M[qt]);
            float p12 = __expf(sfr[2 * chk + 1][qt][2] - M[qt]);
            float p13 = __expf(sfr[2 * chk + 1][qt][3] - M[qt]);
            lsum[qt] += ((p00 + p01) + (p02 + p03)) + ((p10 + p11) + (p12 + p13));
            unsigned w00 = pkbf(p00, p01), w01 = pkbf(p02, p03);
            unsigned w10 = pkbf(p10, p11), w11 = pkbf(p12, p13);
            unsigned a0 = __shfl(w00, src_lo, 64);
            unsigned a1 = __shfl(w10, src_lo, 64);
            unsigned b0 = __shfl(w01, src_lo, 64);
            unsigned b1 = __shfl(w11, src_lo, 64);
            unsigned c0 = __shfl(w00, src_hi, 64);
            unsigned c1 = __shfl(w10, src_hi, 64);
            unsigned d0 = __shfl(w01, src_hi, 64);
            unsigned d1 = __shfl(w11, src_hi, 64);
            union { short8 s8; unsigned u[4]; } P;
            P.u[0] = hisel ? a1 : a0;
            P.u[1] = hisel ? b1 : b0;
            P.u[2] = hisel ? c1 : c0;
            P.u[3] = hisel ? d1 : d0;
            pfrag[qt] = P.s8;
        }
        int jb = 32 * (6 * w + chk);
        short8 vf0 = *(const short8*)&Vt[c * 776 + jb + 8 * g];
        short8 vf1 = *(const short8*)&Vt[(16 + c) * 776 + jb + 8 * g];
#pragma unroll
        for (int qt = 0; qt < 3; ++qt) {
            acc_o[0][qt] = __builtin_amdgcn_mfma_f32_16x16x32_bf16(vf0, pfrag[qt], acc_o[0][qt], 0, 0, 0);
            acc_o[1][qt] = __builtin_amdgcn_mfma_f32_16x16x32_bf16(vf1, pfrag[qt], acc_o[1][qt], 0, 0, 0);
        }
    }

#pragma unroll
    for (int qt = 0; qt < 3; ++qt) {
        lsum[qt] += __shfl_xor(lsum[qt], 16, 64);
        lsum[qt] += __shfl_xor(lsum[qt], 32, 64);
    }
    if (lane < 16) {
#pragma unroll
        for (int qt = 0; qt < 3; ++qt) lred[w][qt][lane] = lsum[qt];
    }
    if (w > 0) {
#pragma unroll
        for (int dt = 0; dt < 2; ++dt)
#pragma unroll
            for (int qt = 0; qt < 3; ++qt)
                *(f32x4*)&Osh[w - 1][dt][qt][lane][0] = acc_o[dt][qt];
    }
    __syncthreads();
    if (w == 0) {
#pragma unroll
        for (int qt = 0; qt < 3; ++qt) {
            int qx = qt * 16 + c;
            if (qx >= 40) continue;
            float L = (lred[0][qt][c] + lred[1][qt][c]) + (lred[2][qt][c] + lred[3][qt][c]);
            float inv = 1.f / L;
#pragma unroll
            for (int dt = 0; dt < 2; ++dt) {
                f32x4 o1 = *(const f32x4*)&Osh[0][dt][qt][lane][0];
                f32x4 o2 = *(const f32x4*)&Osh[1][dt][qt][lane][0];
                f32x4 o3 = *(const f32x4*)&Osh[2][dt][qt][lane][0];
                float4 r;
                r.x = (acc_o[dt][qt][0] + o1[0] + o2[0] + o3[0]) * inv;
                r.y = (acc_o[dt][qt][1] + o1[1] + o2[1] + o3[1]) * inv;
                r.z = (acc_o[dt][qt][2] + o1[2] + o2[2] + o3[2]) * inv;
                r.w = (acc_o[dt][qt][3] + o1[3] + o2[3] + o3[3]) * inv;
                *(float4*)(O + (y * 40 + qx) * ldo + h * HD + dt * 16 + 4 * g) = r;
            }
        }
    }
}

// merged prep: dw_k transpose + [lt|st] weight concat + bias sum
__global__ __launch_bounds__(256) void prep_misc(const float* __restrict__ Kw,
                                                 const float* __restrict__ lt_wo,
                                                 const float* __restrict__ lt_bo,
                                                 const float* __restrict__ st_wo,
                                                 const float* __restrict__ st_bo,
                                                 float* __restrict__ Kt,
                                                 float* __restrict__ wcat,
                                                 float* __restrict__ bsum) {
    int idx = blockIdx.x * 256 + threadIdx.x;   // 0..65535
    int n = idx >> 8, k = idx & 255;
    wcat[n * 512 + k] = lt_wo[idx];
    wcat[n * 512 + 256 + k] = st_wo[idx];
    if (idx < 256) bsum[idx] = lt_bo[idx] + st_bo[idx];
    if (idx < 25 * DFF_) {
        int kk = idx >> 10, c = idx & 1023;
        Kt[idx] = Kw[c * 25 + kk];
    }
}

// GroupNorm partials: grid (32 groups, 8 chunks); deterministic partial sums.
__global__ __launch_bounds__(256) void gn_partial(const float* __restrict__ X,
                                                  float* __restrict__ gstat) {
    __shared__ float sh4[4];
    int g = blockIdx.x, chunk = blockIdx.y;
    int base = g * 32;
    float s = 0.f, s2 = 0.f;
    for (int i = threadIdx.x; i < 200 * 32; i += 256) {
        int l = chunk * 200 + (i >> 5), c = i & 31;
        float v = X[l * DFF_ + base + c];
        s += v;
        s2 += v * v;
    }
    s = blockReduceSum(s, sh4);
    s2 = blockReduceSum(s2, sh4);
    if (threadIdx.x == 0) {
        gstat[g * 8 + chunk] = s;
        gstat[256 + g * 8 + chunk] = s2;
    }
}

// GroupNorm apply + exact GELU, float4-vectorized.
__global__ __launch_bounds__(256) void gn_apply(const float* __restrict__ X,
                                                const float* __restrict__ gstat,
                                                const float* __restrict__ g,
                                                const float* __restrict__ b,
                                                float* __restrict__ Y) {
    int idx = blockIdx.x * 256 + threadIdx.x;
    int e4 = idx * 4;
    int c = e4 & 1023;
    int grp = c >> 5;
    float s = 0.f, s2 = 0.f;
#pragma unroll
    for (int i = 0; i < 8; ++i) {
        s += gstat[grp * 8 + i];
        s2 += gstat[256 + grp * 8 + i];
    }
    const float invn = 1.0f / 51200.f;
    float mean = s * invn;
    float rs = rsqrtf(s2 * invn - mean * mean + 1e-5f);
    float4 v = *(const float4*)(X + e4);
    float4 gg = *(const float4*)(g + c);
    float4 bb = *(const float4*)(b + c);
    float4 r;
    float y0 = (v.x - mean) * rs * gg.x + bb.x;
    float y1 = (v.y - mean) * rs * gg.y + bb.y;
    float y2 = (v.z - mean) * rs * gg.z + bb.z;
    float y3 = (v.w - mean) * rs * gg.w + bb.w;
    r.x = 0.5f * y0 * (1.0f + erff(y0 * 0.70710678118654752f));
    r.y = 0.5f * y1 * (1.0f + erff(y1 * 0.70710678118654752f));
    r.z = 0.5f * y2 * (1.0f + erff(y2 * 0.70710678118654752f));
    r.w = 0.5f * y3 * (1.0f + erff(y3 * 0.70710678118654752f));
    *(float4*)(Y + e4) = r;
}

// depthwise 5x5 conv v2 (verified)
__global__ __launch_bounds__(256) void dwconv_v2(const float* __restrict__ X,
                                                 const float* __restrict__ Kt,
                                                 float* __restrict__ Y) {
    int l = blockIdx.x;
    int c4 = threadIdx.x * 4;
    int y = l / GRID_W, x = l - y * GRID_W;
    float4 acc = make_float4(0.f, 0.f, 0.f, 0.f);
    if (y >= 2 && y < GRID_H - 2 && x >= 2 && x < GRID_W - 2) {
#pragma unroll
        for (int ky = 0; ky < 5; ++ky) {
#pragma unroll
            for (int kx = 0; kx < 5; ++kx) {
                float4 xv = *(const float4*)(X + ((y + ky - 2) * GRID_W + x + kx - 2) * DFF_ + c4);
                float4 wv = *(const float4*)(Kt + (ky * 5 + kx) * DFF_ + c4);
                acc.x += xv.x * wv.x; acc.y += xv.y * wv.y;
                acc.z += xv.z * wv.z; acc.w += xv.w * wv.w;
            }
        }
    } else {
#pragma unroll
        for (int ky = 0; ky < 5; ++ky) {
            int yy = y + ky - 2;
            if (yy < 0 || yy >= GRID_H) continue;
#pragma unroll
            for (int kx = 0; kx < 5; ++kx) {
                int xx = x + kx - 2;
                if (xx < 0 || xx >= GRID_W) continue;
                float4 xv = *(const float4*)(X + (yy * GRID_W + xx) * DFF_ + c4);
                float4 wv = *(const float4*)(Kt + (ky * 5 + kx) * DFF_ + c4);
                acc.x += xv.x * wv.x; acc.y += xv.y * wv.y;
                acc.z += xv.z * wv.z; acc.w += xv.w * wv.w;
            }
        }
    }
    *(float4*)(Y + l * DFF_ + c4) = acc;
}

extern "C" void kernel_launch(void* const* d_in, const int* in_sizes, int n_in,
                              void* d_out, int out_size, void* d_ws, size_t ws_size,
                              hipStream_t stream) {
    (void)in_sizes; (void)n_in; (void)out_size; (void)ws_size;
    const float* tgt = (const float*)d_in[0];
    const float* curr_id_emb = (const float*)d_in[1];
    const float* self_pos = (const float*)d_in[2];
    const float* ln1_g = (const float*)d_in[3];
    const float* ln1_b = (const float*)d_in[4];
    const float* sa_wq = (const float*)d_in[5];
    const float* sa_bq = (const float*)d_in[6];
    const float* sa_wk = (const float*)d_in[7];
    const float* sa_bk = (const float*)d_in[8];
    const float* sa_wv = (const float*)d_in[9];
    const float* sa_bv = (const float*)d_in[10];
    const float* sa_wo = (const float*)d_in[11];
    const float* sa_bo = (const float*)d_in[12];
    const float* ln2_g = (const float*)d_in[13];
    const float* ln2_b = (const float*)d_in[14];
    const float* w_qv = (const float*)d_in[15];
    const float* b_qv = (const float*)d_in[16];
    const float* w_id = (const float*)d_in[17];
    const float* b_id = (const float*)d_in[18];
    const float* lt_wo = (const float*)d_in[19];
    const float* lt_bo = (const float*)d_in[20];
    const float* st_wo = (const float*)d_in[21];
    const float* st_bo = (const float*)d_in[22];
    const float* ln3_g = (const float*)d_in[23];
    const float* ln3_b = (const float*)d_in[24];
    const float* w1 = (const float*)d_in[25];
    const float* b1 = (const float*)d_in[26];
    const float* gn_g = (const float*)d_in[27];
    const float* gn_b = (const float*)d_in[28];
    const float* dw_k = (const float*)d_in[29];
    const float* w2 = (const float*)d_in[30];
    const float* b2 = (const float*)d_in[31];
    float* out = (float*)d_out;

    float* ws = (float*)d_ws;
    const int LC = L_SEQ * CDIM;           // 409600
    float* bufA = ws;                      // ln outputs
    float* bufB = bufA + LC;               // qk_in / tgt_b
    float* bufC = bufB + LC;               // q_
    float* bufD = bufC + LC;               // k_ / gated K (local)
    float* bufE = bufD + LC;               // v_ / gated V (local)
    float* bufG = bufE + LC;               // tgt1
    float* bufFW = bufG + LC;              // attn outs (1600x512)
    float* bufH = bufFW + L_SEQ * 512;     // qv (1600x512); later gstat
    float* bufI = bufH + L_SEQ * 512;      // idkv (1600x264)
    float* bufX = bufI + L_SEQ * 264;      // w1 out (1600x1024)
    float* bufY = bufX + L_SEQ * DFF_;     // gn+gelu out
    float* bufZ = bufY + L_SEQ * DFF_;     // conv out
    float* bufW = bufZ + L_SEQ * DFF_;     // transposed dw_k (25x1024)
    float* wcat = bufW + 25 * DFF_;        // concat lt/st weights (256x512)
    float* bsum = wcat + 256 * 512;        // summed biases (256)
    unsigned short* Kf = (unsigned short*)(bsum + 256);   // NH*13*4096 shorts
    unsigned short* Vf = Kf + NH * NTILE * 4096;          // NH*13*6144 shorts

    dim3 blk(256);
    dim3 mhaGrid(L_SEQ / QBLK, NH);        // (50, 8)
    dim3 prepGrid(NTILE, NH);              // (13, 8)
    auto J = [](const float* A, const float* W, const float* bias, const float* res,
                float* C, int N, int K) {
        GJob j; j.A = A; j.W = W; j.bias = bias; j.res = res; j.C = C; j.N = N; j.K = K;
        return j;
    };

    // 0. merged prep (independent)
    prep_misc<<<256, blk, 0, stream>>>(dw_k, lt_wo, lt_bo, st_wo, st_bo, bufW, wcat, bsum);
    // 1. LN1: bufA = ln(tgt), bufB = bufA + self_pos
    ln_kernel<<<L_SEQ, blk, 0, stream>>>(tgt, ln1_g, ln1_b, self_pos, bufA, bufB);
    // 2. q,k,v projections (one batched dispatch, 300 blocks)
    {
        GJob jq = J(bufB, sa_wq, sa_bq, nullptr, bufC, CDIM, CDIM);
        GJob jk = J(bufB, sa_wk, sa_bk, nullptr, bufD, CDIM, CDIM);
        GJob jv = J(bufA, sa_wv, sa_bv, nullptr, bufE, CDIM, CDIM);
        gemm_mfma<<<dim3(4, 25, 3), blk, 0, stream>>>(jq, jk, jv);
    }
    // 2b. build K/V fragment tiles for self-attn (no plain copy needed)
    prep_kv<<<prepGrid, blk, 0, stream>>>(bufD, CDIM, bufE, CDIM, nullptr, Kf, Vf, nullptr, nullptr);
    // 3. self attention -> bufFW (ldo=256)
    mha_mfma<<<mhaGrid, blk, 0, stream>>>(bufC, CDIM, Kf, Vf, bufFW, CDIM);
    // 4. out proj + residual -> tgt1 (bufG)
    {
        GJob jo = J(bufFW, sa_wo, sa_bo, tgt, bufG, CDIM, CDIM);
        gemm_mfma<<<dim3(4, 25, 1), blk, 0, stream>>>(jo, jo, jo);
    }
    // 5. LN2 -> bufA
    ln_kernel<<<L_SEQ, blk, 0, stream>>>(bufG, ln2_g, ln2_b, nullptr, bufA, nullptr);
    // 6. qv + idkv (one batched dispatch)
    {
        GJob jqv = J(bufA, w_qv, b_qv, nullptr, bufH, 512, CDIM);
        GJob jid = J(curr_id_emb, w_id, b_id, nullptr, bufI, 264, CDIM);
        gemm_mfma<<<dim3(8, 25, 2), blk, 0, stream>>>(jqv, jid, jid);
    }
    // 6b. build gated K/V fragment tiles + plain gated copies (bufD/bufE now dead)
    prep_kv<<<prepGrid, blk, 0, stream>>>(bufH, 512, bufH + 256, 512, bufI, Kf, Vf, bufD, bufE);
    // 7. long-term attention -> bufFW cols 0..255
    mha_mfma<<<mhaGrid, blk, 0, stream>>>(bufH, 512, Kf, Vf, bufFW, 512);
    // 8. local attention (pre-gated contiguous K/V) -> bufFW cols 256..511
    local_mfma<<<dim3(GRID_H, NH), blk, 0, stream>>>(bufH, 512, bufD, CDIM, bufE, CDIM, nullptr, bufFW + 256, 512);
    // 9. merged lt/st projection: tgt_b = tgt1 + [mha2|local] @ wcat^T + bsum -> bufB
    {
        GJob jm = J(bufFW, wcat, bsum, bufG, bufB, CDIM, 512);
        gemm_mfma<<<dim3(4, 25, 1), blk, 0, stream>>>(jm, jm, jm);
    }
    // 10. LN3 -> bufA
    ln_kernel<<<L_SEQ, blk, 0, stream>>>(bufB, ln3_g, ln3_b, nullptr, bufA, nullptr);
    // 11. x = bufA @ w1^T -> bufX
    {
        GJob jw1 = J(bufA, w1, b1, nullptr, bufX, DFF_, CDIM);
        gemm_mfma<<<dim3(16, 25, 1), blk, 0, stream>>>(jw1, jw1, jw1);
    }
    // 12. GroupNorm + GELU -> bufY (bufH dead; reuse as gstat)
    gn_partial<<<dim3(32, 8), blk, 0, stream>>>(bufX, bufH);
    gn_apply<<<L_SEQ, blk, 0, stream>>>(bufX, bufH, gn_g, gn_b, bufY);
    // 13. depthwise conv -> bufZ
    dwconv_v2<<<L_SEQ, blk, 0, stream>>>(bufY, bufW, bufZ);
    // 14. final proj + residual(tgt_b) -> out
    {
        GJob jw2 = J(bufZ, w2, b2, bufB, out, CDIM, DFF_);
        gemm_mfma<<<dim3(4, 25, 1), blk, 0, stream>>>(jw2, jw2, jw2);
    }
}